// Round 1
// baseline (86607.953 us; speedup 1.0000x reference)
//
#include <hip/hip_runtime.h>
#include <math.h>

// ---- problem dims ----
#define Bn    128     // batch
#define Hn    512     // hidden
#define NGn   2048    // 4H gate width
#define TTn   256     // total decoder steps (16 seg x 16 steps)
#define DOn   176     // output dim
#define KAn   688     // decoder L1 K: 176 (note) + 512 (h1)
#define NBLK  512
#define NTHR  256

struct KArgs {
  const float *z, *Wz, *bz;
  const float *cU1, *cb1, *cW2, *cU2, *cb2;
  const float *Wcd, *bcd;
  const float *dW1, *dU1, *db1, *dW2, *dU2, *db2;
  const float *Wp, *bp;
  float *zT, *sT, *h1cT, *ceT, *sdT, *beffT, *xbuf, *c1T, *h2T, *c2T;
  float *out;
};

// self-resetting grid-barrier state (returns to all-zero after every barrier,
// so graph replays are deterministic; g_gen only ever compared to a snapshot)
__device__ unsigned g_cnt_l1[16];
__device__ unsigned g_cnt;
__device__ unsigned g_gen;

__device__ __forceinline__ float sigm(float x) { return 1.0f / (1.0f + __expf(-x)); }

__device__ __forceinline__ void gbar() {
  __syncthreads();
  if (threadIdx.x == 0) {
    unsigned g0 = __hip_atomic_load(&g_gen, __ATOMIC_RELAXED, __HIP_MEMORY_SCOPE_AGENT);
    int grp = blockIdx.x >> 5;  // 16 groups of 32 blocks
    unsigned p1 = __hip_atomic_fetch_add(&g_cnt_l1[grp], 1u, __ATOMIC_ACQ_REL, __HIP_MEMORY_SCOPE_AGENT);
    bool done = false;
    if (p1 == 31u) {
      unsigned p2 = __hip_atomic_fetch_add(&g_cnt, 1u, __ATOMIC_ACQ_REL, __HIP_MEMORY_SCOPE_AGENT);
      if (p2 == 15u) {
        #pragma unroll
        for (int i = 0; i < 16; i++)
          __hip_atomic_store(&g_cnt_l1[i], 0u, __ATOMIC_RELAXED, __HIP_MEMORY_SCOPE_AGENT);
        __hip_atomic_store(&g_cnt, 0u, __ATOMIC_RELAXED, __HIP_MEMORY_SCOPE_AGENT);
        __hip_atomic_fetch_add(&g_gen, 1u, __ATOMIC_RELEASE, __HIP_MEMORY_SCOPE_AGENT);
        done = true;
      }
    }
    if (!done) {
      while (__hip_atomic_load(&g_gen, __ATOMIC_RELAXED, __HIP_MEMORY_SCOPE_AGENT) == g0)
        __builtin_amdgcn_s_sleep(2);
      __threadfence();
    }
  }
  __syncthreads();
}

// ---------------- preamble phases ----------------

// P0: S = tanh(z @ Wz + bz)   (128 x 2048), stored transposed sT[n][b]
__device__ __forceinline__ void pre0(const KArgs& a) {
  const int wid = threadIdx.x >> 6, lane = threadIdx.x & 63;
  const int W = blockIdx.x * 4 + wid;      // 0..2047
  const int n = W >> 1, bh = W & 1, b = bh * 64 + lane;
  float a0 = 0.f, a1 = 0.f;
  for (int k = 0; k < 512; k++) {
    const float xv = a.zT[(size_t)k * Bn + b];
    a0 = fmaf(xv, a.Wz[(size_t)k * NGn + n],        a0);
    a1 = fmaf(xv, a.Wz[(size_t)k * NGn + n + 1024], a1);
  }
  a.sT[(size_t)n * Bn + b]          = tanhf(a0 + a.bz[n]);
  a.sT[(size_t)(n + 1024) * Bn + b] = tanhf(a1 + a.bz[n + 1024]);
}

// P1: conductor L1 with x=0:  g = ch1 @ cU1 + cb1 -> h1c
__device__ __forceinline__ void pre1(const KArgs& a, float* lds) {
  const int tid = threadIdx.x, wid = tid >> 6, lane = tid & 63;
  const int j = blockIdx.x;                 // 0..511
  const int bh = wid & 1, kh = wid >> 1;
  const int b = bh * 64 + lane;
  float acc[4];
  #pragma unroll
  for (int g = 0; g < 4; g++) acc[g] = (kh == 0) ? a.cb1[g * Hn + j] : 0.0f;
  const int k0 = kh * 256;
  for (int k = k0; k < k0 + 256; k++) {
    const float xv = a.sT[(size_t)k * Bn + b];          // ch1 rows 0..511
    const float* wrow = a.cU1 + (size_t)k * NGn;
    #pragma unroll
    for (int g = 0; g < 4; g++) acc[g] = fmaf(xv, wrow[g * Hn + j], acc[g]);
  }
  if (kh == 1) {
    #pragma unroll
    for (int g = 0; g < 4; g++) lds[(bh * 4 + g) * 64 + lane] = acc[g];
  }
  __syncthreads();
  if (kh == 0) {
    #pragma unroll
    for (int g = 0; g < 4; g++) acc[g] += lds[(bh * 4 + g) * 64 + lane];
    const float iv = sigm(acc[0]), fv = sigm(acc[1]);
    const float gv = tanhf(acc[2]), ov = sigm(acc[3]);
    const float cp = a.sT[(size_t)(Hn + j) * Bn + b];   // cc1 rows 512..1023
    const float c = fv * cp + iv * gv;
    a.h1cT[(size_t)j * Bn + b] = ov * tanhf(c);
  }
}

// P2: conductor L2: g = h1c @ cW2 + ch2 @ cU2 + cb2 -> cond_emb
__device__ __forceinline__ void pre2(const KArgs& a, float* lds) {
  const int tid = threadIdx.x, wid = tid >> 6, lane = tid & 63;
  const int j = blockIdx.x;
  const int bh = wid & 1, kh = wid >> 1;
  const int b = bh * 64 + lane;
  float acc[4];
  #pragma unroll
  for (int g = 0; g < 4; g++) acc[g] = (kh == 0) ? a.cb2[g * Hn + j] : 0.0f;
  if (kh == 0) {
    for (int k = 0; k < 512; k++) {
      const float xv = a.h1cT[(size_t)k * Bn + b];
      const float* wrow = a.cW2 + (size_t)k * NGn;
      #pragma unroll
      for (int g = 0; g < 4; g++) acc[g] = fmaf(xv, wrow[g * Hn + j], acc[g]);
    }
  } else {
    for (int k = 0; k < 512; k++) {
      const float xv = a.sT[(size_t)(1024 + k) * Bn + b];   // ch2 rows
      const float* wrow = a.cU2 + (size_t)k * NGn;
      #pragma unroll
      for (int g = 0; g < 4; g++) acc[g] = fmaf(xv, wrow[g * Hn + j], acc[g]);
    }
  }
  if (kh == 1) {
    #pragma unroll
    for (int g = 0; g < 4; g++) lds[(bh * 4 + g) * 64 + lane] = acc[g];
  }
  __syncthreads();
  if (kh == 0) {
    #pragma unroll
    for (int g = 0; g < 4; g++) acc[g] += lds[(bh * 4 + g) * 64 + lane];
    const float iv = sigm(acc[0]), fv = sigm(acc[1]);
    const float gv = tanhf(acc[2]), ov = sigm(acc[3]);
    const float cp = a.sT[(size_t)(1536 + j) * Bn + b];  // cc2 rows
    const float c = fv * cp + iv * gv;
    a.ceT[(size_t)j * Bn + b] = ov * tanhf(c);
  }
}

// P3: sd = tanh(ce @ Wcd + bcd)  and  b1_eff = db1 + ce @ dW1[176:,:]
__device__ __forceinline__ void pre3(const KArgs& a) {
  const int wid = threadIdx.x >> 6, lane = threadIdx.x & 63;
  const int W = blockIdx.x * 4 + wid;
  const int n = W >> 1, bh = W & 1, b = bh * 64 + lane;
  float s0 = 0.f, s1 = 0.f, e0 = 0.f, e1 = 0.f;
  for (int k = 0; k < 512; k++) {
    const float xv = a.ceT[(size_t)k * Bn + b];
    s0 = fmaf(xv, a.Wcd[(size_t)k * NGn + n],            s0);
    s1 = fmaf(xv, a.Wcd[(size_t)k * NGn + n + 1024],     s1);
    e0 = fmaf(xv, a.dW1[(size_t)(176 + k) * NGn + n],        e0);
    e1 = fmaf(xv, a.dW1[(size_t)(176 + k) * NGn + n + 1024], e1);
  }
  a.sdT[(size_t)n * Bn + b]            = tanhf(s0 + a.bcd[n]);
  a.sdT[(size_t)(n + 1024) * Bn + b]   = tanhf(s1 + a.bcd[n + 1024]);
  a.beffT[(size_t)n * Bn + b]          = e0 + a.db1[n];
  a.beffT[(size_t)(n + 1024) * Bn + b] = e1 + a.db1[n + 1024];
}

// ---------------- main-loop phases ----------------

// Phase A: decoder L1 LSTM.  g = note@dW1[:176] + h1@dU1 + b1_eff -> h1',c1'
__device__ __forceinline__ void phaseA(const KArgs& a, float* lds, int t, int cur) {
  const int tid = threadIdx.x, wid = tid >> 6, lane = tid & 63;
  const int jblk = blockIdx.x >> 1, bh = blockIdx.x & 1;
  const int b = bh * 64 + lane;
  const int j0 = jblk * 2;
  const bool rst = (t & 15) == 0;
  const float* xb = a.xbuf + (size_t)cur * (KAn * Bn);
  const float* hb = rst ? (a.sdT - 176 * Bn) : xb;   // dh1T rows 0..511 at sdT
  float acc[8];
  if (wid == 0) {
    #pragma unroll
    for (int u = 0; u < 2; u++) {
      #pragma unroll
      for (int g = 0; g < 4; g++)
        acc[u * 4 + g] = a.beffT[(size_t)(g * Hn + j0 + u) * Bn + b];
    }
  } else {
    #pragma unroll
    for (int i = 0; i < 8; i++) acc[i] = 0.0f;
  }
  const int k0 = wid * 172;
  for (int k = k0; k < k0 + 172; k++) {
    const float xv = ((k < 176) ? xb : hb)[(size_t)k * Bn + b];
    const float* wrow = (k < 176) ? (a.dW1 + (size_t)k * NGn)
                                  : (a.dU1 + (size_t)(k - 176) * NGn);
    #pragma unroll
    for (int g = 0; g < 4; g++) {
      acc[g]     = fmaf(xv, wrow[g * Hn + j0],     acc[g]);
      acc[4 + g] = fmaf(xv, wrow[g * Hn + j0 + 1], acc[4 + g]);
    }
  }
  if (wid > 0) {
    #pragma unroll
    for (int i = 0; i < 8; i++) lds[((wid - 1) * 8 + i) * 64 + lane] = acc[i];
  }
  __syncthreads();
  if (wid == 0) {
    #pragma unroll
    for (int i = 0; i < 8; i++)
      acc[i] += lds[i * 64 + lane] + lds[(8 + i) * 64 + lane] + lds[(16 + i) * 64 + lane];
    float* xn = a.xbuf + (size_t)(cur ^ 1) * (KAn * Bn);
    #pragma unroll
    for (int u = 0; u < 2; u++) {
      const int j = j0 + u;
      const float iv = sigm(acc[u * 4 + 0]);
      const float fv = sigm(acc[u * 4 + 1]);
      const float gv = tanhf(acc[u * 4 + 2]);
      const float ov = sigm(acc[u * 4 + 3]);
      const float cp = rst ? a.sdT[(size_t)(Hn + j) * Bn + b] : a.c1T[(size_t)j * Bn + b];
      const float c  = fv * cp + iv * gv;
      a.c1T[(size_t)j * Bn + b] = c;
      xn[(size_t)(176 + j) * Bn + b] = ov * tanhf(c);
    }
  }
}

// Phase B: decoder L2 LSTM.  g = h1'@dW2 + h2@dU2 + db2 -> h2',c2'
__device__ __forceinline__ void phaseB(const KArgs& a, float* lds, int t, int cur) {
  const int tid = threadIdx.x, wid = tid >> 6, lane = tid & 63;
  const int jblk = blockIdx.x >> 1, bh = blockIdx.x & 1;
  const int b = bh * 64 + lane;
  const int j0 = jblk * 2;
  const bool rst = (t & 15) == 0;
  const float* xn  = a.xbuf + (size_t)(cur ^ 1) * (KAn * Bn) + 176 * Bn; // h1' rows
  const float* h2b = rst ? (a.sdT + 1024 * Bn) : (a.h2T + (size_t)cur * (Hn * Bn));
  float acc[8];
  if (wid == 0) {
    #pragma unroll
    for (int u = 0; u < 2; u++) {
      #pragma unroll
      for (int g = 0; g < 4; g++)
        acc[u * 4 + g] = a.db2[g * Hn + j0 + u];
    }
  } else {
    #pragma unroll
    for (int i = 0; i < 8; i++) acc[i] = 0.0f;
  }
  const int k0 = wid * 256;
  const float* xr = (k0 < 512) ? (xn + (size_t)k0 * Bn) : (h2b + (size_t)(k0 - 512) * Bn);
  const float* wb = (k0 < 512) ? (a.dW2 + (size_t)k0 * NGn) : (a.dU2 + (size_t)(k0 - 512) * NGn);
  for (int kk = 0; kk < 256; kk++) {
    const float xv = xr[(size_t)kk * Bn + b];
    const float* wrow = wb + (size_t)kk * NGn;
    #pragma unroll
    for (int g = 0; g < 4; g++) {
      acc[g]     = fmaf(xv, wrow[g * Hn + j0],     acc[g]);
      acc[4 + g] = fmaf(xv, wrow[g * Hn + j0 + 1], acc[4 + g]);
    }
  }
  if (wid > 0) {
    #pragma unroll
    for (int i = 0; i < 8; i++) lds[((wid - 1) * 8 + i) * 64 + lane] = acc[i];
  }
  __syncthreads();
  if (wid == 0) {
    #pragma unroll
    for (int i = 0; i < 8; i++)
      acc[i] += lds[i * 64 + lane] + lds[(8 + i) * 64 + lane] + lds[(16 + i) * 64 + lane];
    float* h2n = a.h2T + (size_t)(cur ^ 1) * (Hn * Bn);
    #pragma unroll
    for (int u = 0; u < 2; u++) {
      const int j = j0 + u;
      const float iv = sigm(acc[u * 4 + 0]);
      const float fv = sigm(acc[u * 4 + 1]);
      const float gv = tanhf(acc[u * 4 + 2]);
      const float ov = sigm(acc[u * 4 + 3]);
      const float cp = rst ? a.sdT[(size_t)(1536 + j) * Bn + b] : a.c2T[(size_t)j * Bn + b];
      const float c  = fv * cp + iv * gv;
      a.c2T[(size_t)j * Bn + b] = c;
      h2n[(size_t)j * Bn + b] = ov * tanhf(c);
    }
  }
}

// Phase C: logits = h2' @ Wp + bp ; softmax ; write note(next) + output
__device__ __forceinline__ void phaseC(const KArgs& a, float* lds, int t, int cur) {
  if (blockIdx.x >= Bn) return;
  const int b = blockIdx.x, o = threadIdx.x;
  const float* h2n = a.h2T + (size_t)(cur ^ 1) * (Hn * Bn);
  float acc = -1e30f;
  if (o < DOn) {
    acc = a.bp[o];
    for (int k = 0; k < 512; k++)
      acc = fmaf(h2n[(size_t)k * Bn + b], a.Wp[(size_t)k * DOn + o], acc);
  }
  lds[o] = acc; __syncthreads();
  for (int s = 128; s > 0; s >>= 1) {
    if (o < s) lds[o] = fmaxf(lds[o], lds[o + s]);
    __syncthreads();
  }
  const float mx = lds[0]; __syncthreads();
  const float e = (o < DOn) ? __expf(acc - mx) : 0.0f;
  lds[o] = e; __syncthreads();
  for (int s = 128; s > 0; s >>= 1) {
    if (o < s) lds[o] += lds[o + s];
    __syncthreads();
  }
  const float inv = 1.0f / lds[0];
  if (o < DOn) {
    const float p = e * inv;
    a.xbuf[(size_t)(cur ^ 1) * (KAn * Bn) + (size_t)o * Bn + b] = p;  // noteT next
    a.out[((size_t)b * TTn + t) * DOn + o] = p;
  }
}

__global__ void __launch_bounds__(NTHR, 2)
hd_kernel(KArgs a) {
  __shared__ float lds[1600];
  // P-1: transpose z, zero initial note rows of xbuf[0]
  {
    const int T = blockIdx.x * NTHR + threadIdx.x;
    if (T < 512 * Bn) {
      const int zb = T >> 9, zk = T & 511;
      a.zT[(size_t)zk * Bn + zb] = a.z[T];
    }
    const int T2 = T - 512 * Bn;
    if (T2 >= 0 && T2 < 176 * Bn) a.xbuf[T2] = 0.0f;
  }
  gbar();
  pre0(a); gbar();
  pre1(a, lds); gbar();
  pre2(a, lds); gbar();
  pre3(a); gbar();
  for (int t = 0; t < TTn; t++) {
    const int cur = t & 1;
    phaseA(a, lds, t, cur); gbar();
    phaseB(a, lds, t, cur); gbar();
    phaseC(a, lds, t, cur); gbar();
  }
}

extern "C" void kernel_launch(void* const* d_in, const int* in_sizes, int n_in,
                              void* d_out, int out_size, void* d_ws, size_t ws_size,
                              hipStream_t stream) {
  (void)in_sizes; (void)n_in; (void)out_size; (void)ws_size;
  KArgs a;
  a.z   = (const float*)d_in[0];
  a.Wz  = (const float*)d_in[3];  a.bz  = (const float*)d_in[4];
  // d_in[5] = cond_W1 is unused (conductor input x0 == 0)
  a.cU1 = (const float*)d_in[6];  a.cb1 = (const float*)d_in[7];
  a.cW2 = (const float*)d_in[8];  a.cU2 = (const float*)d_in[9];  a.cb2 = (const float*)d_in[10];
  a.Wcd = (const float*)d_in[11]; a.bcd = (const float*)d_in[12];
  a.dW1 = (const float*)d_in[13]; a.dU1 = (const float*)d_in[14]; a.db1 = (const float*)d_in[15];
  a.dW2 = (const float*)d_in[16]; a.dU2 = (const float*)d_in[17]; a.db2 = (const float*)d_in[18];
  a.Wp  = (const float*)d_in[19]; a.bp  = (const float*)d_in[20];

  float* ws = (float*)d_ws;
  size_t off = 0;
  a.zT    = ws + off; off += (size_t)512  * Bn;
  a.sT    = ws + off; off += (size_t)2048 * Bn;
  a.h1cT  = ws + off; off += (size_t)512  * Bn;
  a.ceT   = ws + off; off += (size_t)512  * Bn;
  a.sdT   = ws + off; off += (size_t)2048 * Bn;   // dh1|dc1|dh2|dc2 transposed
  a.beffT = ws + off; off += (size_t)2048 * Bn;
  a.xbuf  = ws + off; off += (size_t)2 * KAn * Bn; // [note(176)|h1(512)] x2 transposed
  a.c1T   = ws + off; off += (size_t)512  * Bn;
  a.h2T   = ws + off; off += (size_t)2 * 512 * Bn;
  a.c2T   = ws + off; off += (size_t)512  * Bn;
  a.out   = (float*)d_out;

  hd_kernel<<<dim3(NBLK), dim3(NTHR), 0, stream>>>(a);
}

// Round 2
// 36501.126 us; speedup vs baseline: 2.3727x; 2.3727x over previous
//
#include <hip/hip_runtime.h>
#include <math.h>

// ---- problem dims ----
#define Bn    128     // batch
#define Hn    512     // hidden
#define NGn   2048    // 4H gate width
#define TTn   256     // total decoder steps
#define DOn   176     // output dim
#define KAn   688     // decoder L1 K: 176 (note) + 512 (h1)
#define NBLK  256
#define NTHR  512

struct KArgs {
  const float *z, *Wz, *bz;
  const float *cU1, *cb1, *cW2, *cU2, *cb2;
  const float *Wcd, *bcd;
  const float *dW1, *dU1, *db1, *dW2, *dU2, *db2;
  const float *Wp, *bp;
  float *zT, *sT, *gbuf, *h1cT, *ceT, *sdT, *beffT, *xbufA, *h2T, *c1T, *c2T, *h2bk;
  float *WAp, *WEp, *WBp, *db1p, *db2p;
  float *out;
};

// self-resetting grid barrier (all counters return to 0 after each use)
__device__ unsigned g_cnt_l1[16];
__device__ unsigned g_cnt;
__device__ unsigned g_gen;

__device__ __forceinline__ float sigm(float x) { return 1.0f / (1.0f + __expf(-x)); }

__device__ __forceinline__ void gbar() {
  __syncthreads();
  if (threadIdx.x == 0) {
    unsigned g0 = __hip_atomic_load(&g_gen, __ATOMIC_RELAXED, __HIP_MEMORY_SCOPE_AGENT);
    int grp = blockIdx.x >> 4;  // 16 groups of 16 blocks
    unsigned p1 = __hip_atomic_fetch_add(&g_cnt_l1[grp], 1u, __ATOMIC_ACQ_REL, __HIP_MEMORY_SCOPE_AGENT);
    if (p1 == 15u) {
      unsigned p2 = __hip_atomic_fetch_add(&g_cnt, 1u, __ATOMIC_ACQ_REL, __HIP_MEMORY_SCOPE_AGENT);
      if (p2 == 15u) {
        #pragma unroll
        for (int i = 0; i < 16; i++)
          __hip_atomic_store(&g_cnt_l1[i], 0u, __ATOMIC_RELAXED, __HIP_MEMORY_SCOPE_AGENT);
        __hip_atomic_store(&g_cnt, 0u, __ATOMIC_RELAXED, __HIP_MEMORY_SCOPE_AGENT);
        __hip_atomic_fetch_add(&g_gen, 1u, __ATOMIC_RELEASE, __HIP_MEMORY_SCOPE_AGENT);
      }
    }
    while (__hip_atomic_load(&g_gen, __ATOMIC_RELAXED, __HIP_MEMORY_SCOPE_AGENT) == g0)
      __builtin_amdgcn_s_sleep(1);
    __threadfence();   // acquire: invalidate L1 so fresh producer data is visible
  }
  __syncthreads();
}

#define FMA16(W, V0, V1, V2, V3)                                                              \
  acc[0] = fmaf(W, V0.x, acc[0]);  acc[1] = fmaf(W, V0.y, acc[1]);                            \
  acc[2] = fmaf(W, V0.z, acc[2]);  acc[3] = fmaf(W, V0.w, acc[3]);                            \
  acc[4] = fmaf(W, V1.x, acc[4]);  acc[5] = fmaf(W, V1.y, acc[5]);                            \
  acc[6] = fmaf(W, V1.z, acc[6]);  acc[7] = fmaf(W, V1.w, acc[7]);                            \
  acc[8] = fmaf(W, V2.x, acc[8]);  acc[9] = fmaf(W, V2.y, acc[9]);                            \
  acc[10] = fmaf(W, V2.z, acc[10]); acc[11] = fmaf(W, V2.w, acc[11]);                         \
  acc[12] = fmaf(W, V3.x, acc[12]); acc[13] = fmaf(W, V3.y, acc[13]);                         \
  acc[14] = fmaf(W, V3.z, acc[14]); acc[15] = fmaf(W, V3.w, acc[15]);

// Block GEMM: out-tile = 64 cols (lane) x 16 batch (acc regs), 8-wave k-split.
// Wave w handles k in [w*KC, (w+1)*KC). If k0 >= K1, switch to (W2, X2) bases.
// Writes per-wave partials to lds[(wid*64+lane)*20 + 0..15].
template<int KC>
__device__ __forceinline__ void gemm8(const float* __restrict__ W1, const float* __restrict__ W2,
                                      int K1,
                                      const float* __restrict__ X1, const float* __restrict__ X2,
                                      int colbase, int b0, int wid, int lane,
                                      float* __restrict__ lds)
{
  const int k0 = wid * KC;
  const float* wp;
  const float* xp;
  if (k0 < K1) {
    wp = W1 + (size_t)k0 * NGn + colbase + lane;
    xp = X1 + (size_t)k0 * Bn + b0;
  } else {
    wp = W2 + (size_t)(k0 - K1) * NGn + colbase + lane;
    xp = X2 + (size_t)(k0 - K1) * Bn + b0;
  }
  float acc[16];
  #pragma unroll
  for (int i = 0; i < 16; i++) acc[i] = 0.0f;
  for (int kk = 0; kk < KC; kk += 2) {
    const float w0 = wp[0];
    const float w1 = wp[NGn];
    const float4 x0 = *(const float4*)(xp + 0);
    const float4 x1 = *(const float4*)(xp + 4);
    const float4 x2 = *(const float4*)(xp + 8);
    const float4 x3 = *(const float4*)(xp + 12);
    const float4 y0 = *(const float4*)(xp + Bn + 0);
    const float4 y1 = *(const float4*)(xp + Bn + 4);
    const float4 y2 = *(const float4*)(xp + Bn + 8);
    const float4 y3 = *(const float4*)(xp + Bn + 12);
    FMA16(w0, x0, x1, x2, x3)
    FMA16(w1, y0, y1, y2, y3)
    wp += 2 * NGn;
    xp += 2 * Bn;
  }
  float* base = lds + ((size_t)wid * 64 + lane) * 20;
  #pragma unroll
  for (int i = 0; i < 16; i += 4)
    *(float4*)(base + i) = make_float4(acc[i], acc[i + 1], acc[i + 2], acc[i + 3]);
}

// plain epilogue: out[col][b] = f(sum8 + bias[col]); MODE 0 = tanh, 1 = identity
template<int MODE>
__device__ __forceinline__ void epi_plain(const float* bias, float* out,
                                          int colbase, int b0, int tid, const float* lds)
{
  __syncthreads();
  #pragma unroll
  for (int rep = 0; rep < 2; rep++) {
    int e = tid + rep * NTHR;       // 0..1023
    int cl = e >> 4, bl = e & 15;
    float s = 0.0f;
    #pragma unroll
    for (int w = 0; w < 8; w++) s += lds[(w * 64 + cl) * 20 + bl];
    if (bias) s += bias[colbase + cl];
    if (MODE == 0) s = tanhf(s);
    out[(size_t)(colbase + cl) * Bn + b0 + bl] = s;
  }
}

// decoder L1 LSTM epilogue (perm cols: cl = h*4+g, bias = beffT per (col,b))
__device__ __forceinline__ void epi_lstmA(const KArgs& a, int ht, int b0, int tid,
                                          const float* lds, bool rst, float* xn)
{
  __syncthreads();
  if (tid < 256) {
    int h = tid >> 4, bl = tid & 15;
    int hid = ht * 16 + h, b = b0 + bl;
    float g4[4];
    #pragma unroll
    for (int g = 0; g < 4; g++) {
      int cl = h * 4 + g;
      float s = 0.0f;
      #pragma unroll
      for (int w = 0; w < 8; w++) s += lds[(w * 64 + cl) * 20 + bl];
      g4[g] = s + a.beffT[(size_t)(ht * 64 + cl) * Bn + b];
    }
    float cprev = rst ? a.sdT[(size_t)(Hn + hid) * Bn + b] : a.c1T[(size_t)hid * Bn + b];
    float c = sigm(g4[1]) * cprev + sigm(g4[0]) * tanhf(g4[2]);
    a.c1T[(size_t)hid * Bn + b] = c;
    xn[(size_t)(DOn + hid) * Bn + b] = sigm(g4[3]) * tanhf(c);
  }
}

// decoder L2 LSTM epilogue
__device__ __forceinline__ void epi_lstmB(const KArgs& a, int ht, int b0, int tid,
                                          const float* lds, bool rst, float* h2n)
{
  __syncthreads();
  if (tid < 256) {
    int h = tid >> 4, bl = tid & 15;
    int hid = ht * 16 + h, b = b0 + bl;
    float g4[4];
    #pragma unroll
    for (int g = 0; g < 4; g++) {
      int cl = h * 4 + g;
      float s = 0.0f;
      #pragma unroll
      for (int w = 0; w < 8; w++) s += lds[(w * 64 + cl) * 20 + bl];
      g4[g] = s + a.db2p[ht * 64 + cl];
    }
    float cprev = rst ? a.sdT[(size_t)(1536 + hid) * Bn + b] : a.c2T[(size_t)hid * Bn + b];
    float c = sigm(g4[1]) * cprev + sigm(g4[0]) * tanhf(g4[2]);
    a.c2T[(size_t)hid * Bn + b] = c;
    float h2 = sigm(g4[3]) * tanhf(c);
    h2n[(size_t)hid * Bn + b] = h2;
    a.h2bk[(size_t)b * Hn + hid] = h2;   // [b][k] copy for phase C
  }
}

// conductor LSTM nonlinearity from plain-layout raw gates in gbuf
__device__ __forceinline__ void cond_nl(const KArgs& a, const float* cbias, const float* cin,
                                        float* hout, int bid, int tid)
{
  int i = bid * NTHR + tid;
  if (i < Hn * Bn) {
    int hid = i >> 7, b = i & 127;
    float gi = a.gbuf[(size_t)hid * Bn + b]            + cbias[hid];
    float gf = a.gbuf[(size_t)(Hn + hid) * Bn + b]     + cbias[Hn + hid];
    float gg = a.gbuf[(size_t)(2 * Hn + hid) * Bn + b] + cbias[2 * Hn + hid];
    float go = a.gbuf[(size_t)(3 * Hn + hid) * Bn + b] + cbias[3 * Hn + hid];
    float cprev = cin[(size_t)hid * Bn + b];
    float c = sigm(gf) * cprev + sigm(gi) * tanhf(gg);
    hout[(size_t)hid * Bn + b] = sigm(go) * tanhf(c);
  }
}

__global__ void __launch_bounds__(NTHR, 2)
hd_kernel(KArgs a) {
  __shared__ float lds[10240];   // 40 KB: 8 waves x 64 lanes x 20 (16 used + pad)
  const int bid = blockIdx.x, tid = threadIdx.x;
  const int wid = tid >> 6, lane = tid & 63;
  // swizzle so XCD x (bid%8==x) owns col-tiles 4x..4x+3 for all batch tiles:
  // its weight slice (~1.8 MB) stays L2-resident across all 256 steps.
  const int ht = (bid & 7) * 4 + ((bid >> 3) & 3);   // col-tile 0..31 (16 hidden each)
  const int bt = bid >> 5;                           // batch tile 0..7 (16 each)
  const int colbase = ht * 64, b0 = bt * 16;

  // ---- P-1: transposes, zero init, bias + weight permutes ----
  {
    int i = bid * NTHR + tid;                        // 0..131071
    if (i < Hn * Bn) { int zb = i >> 9, zk = i & 511; a.zT[(size_t)zk * Bn + zb] = a.z[i]; }
    int i2 = i - Hn * Bn;
    if (i2 >= 0 && i2 < DOn * Bn) a.xbufA[i2] = 0.0f;
    if (i < NGn) {
      int g = i & 3, hid = ((i >> 6) << 4) | ((i >> 2) & 15);
      int col = g * Hn + hid;
      a.db1p[i] = a.db1[col];
      a.db2p[i] = a.db2[col];
    }
    const int NA = KAn * NGn;
    for (int j = i; j < NA; j += NBLK * NTHR) {
      int k = j >> 11, pc = j & 2047;
      int g = pc & 3, hid = ((pc >> 6) << 4) | ((pc >> 2) & 15);
      int col = g * Hn + hid;
      a.WAp[j] = (k < DOn) ? a.dW1[(size_t)k * NGn + col] : a.dU1[(size_t)(k - DOn) * NGn + col];
    }
    const int NE = Hn * NGn;
    for (int j = i; j < NE; j += NBLK * NTHR) {
      int k = j >> 11, pc = j & 2047;
      int g = pc & 3, hid = ((pc >> 6) << 4) | ((pc >> 2) & 15);
      a.WEp[j] = a.dW1[(size_t)(DOn + k) * NGn + g * Hn + hid];
    }
    const int NB = 1024 * NGn;
    for (int j = i; j < NB; j += NBLK * NTHR) {
      int k = j >> 11, pc = j & 2047;
      int g = pc & 3, hid = ((pc >> 6) << 4) | ((pc >> 2) & 15);
      int col = g * Hn + hid;
      a.WBp[j] = (k < Hn) ? a.dW2[(size_t)k * NGn + col] : a.dU2[(size_t)(k - Hn) * NGn + col];
    }
  }
  gbar();
  // ---- P0: S = tanh(z @ Wz + bz) -> sT (plain cols) ----
  gemm8<64>(a.Wz, nullptr, 1 << 20, a.zT, nullptr, colbase, b0, wid, lane, lds);
  epi_plain<0>(a.bz, a.sT, colbase, b0, tid, lds);
  gbar();
  // ---- P1: conductor L1 raw gates = ch1 @ cU1 -> gbuf ----
  gemm8<64>(a.cU1, nullptr, 1 << 20, a.sT, nullptr, colbase, b0, wid, lane, lds);
  epi_plain<1>(nullptr, a.gbuf, colbase, b0, tid, lds);
  gbar();
  // ---- P1b: nonlin -> h1cT ----
  cond_nl(a, a.cb1, a.sT + (size_t)Hn * Bn, a.h1cT, bid, tid);
  gbar();
  // ---- P2: conductor L2 raw gates = h1c @ cW2 + ch2 @ cU2 -> gbuf ----
  gemm8<128>(a.cW2, a.cU2, Hn, a.h1cT, a.sT + (size_t)1024 * Bn, colbase, b0, wid, lane, lds);
  epi_plain<1>(nullptr, a.gbuf, colbase, b0, tid, lds);
  gbar();
  // ---- P2b: nonlin -> ceT ----
  cond_nl(a, a.cb2, a.sT + (size_t)1536 * Bn, a.ceT, bid, tid);
  gbar();
  // ---- P3: sd = tanh(ce @ Wcd + bcd) -> sdT ; beff = db1p + ce @ WEp -> beffT ----
  gemm8<64>(a.Wcd, nullptr, 1 << 20, a.ceT, nullptr, colbase, b0, wid, lane, lds);
  epi_plain<0>(a.bcd, a.sdT, colbase, b0, tid, lds);
  __syncthreads();
  gemm8<64>(a.WEp, nullptr, 1 << 20, a.ceT, nullptr, colbase, b0, wid, lane, lds);
  epi_plain<1>(a.db1p, a.beffT, colbase, b0, tid, lds);
  gbar();
  // ---- P4: state init: dh1 -> xbufA[0] rows 176.., dh2 -> h2T[0] ----
  {
    int i = bid * NTHR + tid;
    if (i < Hn * Bn) {
      a.xbufA[(size_t)DOn * Bn + i] = a.sdT[i];
      a.h2T[i] = a.sdT[(size_t)1024 * Bn + i];
    }
  }
  gbar();

  // ---- main loop ----
  for (int t = 0; t < TTn; t++) {
    const int cur = t & 1;
    float* xc  = a.xbufA + (size_t)cur * (KAn * Bn);
    float* xn  = a.xbufA + (size_t)(cur ^ 1) * (KAn * Bn);
    float* h2c = a.h2T + (size_t)cur * (Hn * Bn);
    float* h2n = a.h2T + (size_t)(cur ^ 1) * (Hn * Bn);
    const bool rst = (t & 15) == 0;

    // phase A: decoder L1 (K = 688 contiguous: [note | h1])
    gemm8<86>(a.WAp, nullptr, 1 << 20, xc, nullptr, colbase, b0, wid, lane, lds);
    epi_lstmA(a, ht, b0, tid, lds, rst, xn);
    gbar();

    // phase B: decoder L2 (K = 1024: waves 0-3 h1' @ dW2, waves 4-7 h2 @ dU2)
    gemm8<128>(a.WBp, a.WBp + (size_t)Hn * NGn, Hn, xn + (size_t)DOn * Bn, h2c,
               colbase, b0, wid, lane, lds);
    epi_lstmB(a, ht, b0, tid, lds, rst, h2n);
    gbar();

    // phase C: projection + softmax (blocks 0..127), segment-reset copies (blocks 128+)
    if (bid < Bn) {
      const int b = bid;
      const int ks = tid >> 8;     // 0 or 1
      const int o = tid & 255;
      float acc = 0.0f;
      if (o < DOn) {
        const float* xr = a.h2bk + (size_t)b * Hn + ks * 256;
        const float* wr = a.Wp + (size_t)(ks * 256) * DOn + o;
        if (ks == 0) acc = a.bp[o];
        for (int k = 0; k < 256; k += 4) {
          const float4 xv = *(const float4*)(xr + k);
          acc = fmaf(xv.x, wr[(size_t)(k + 0) * DOn], acc);
          acc = fmaf(xv.y, wr[(size_t)(k + 1) * DOn], acc);
          acc = fmaf(xv.z, wr[(size_t)(k + 2) * DOn], acc);
          acc = fmaf(xv.w, wr[(size_t)(k + 3) * DOn], acc);
        }
        lds[ks * DOn + o] = acc;
      }
      __syncthreads();
      if (tid < DOn) lds[512 + tid] = lds[tid] + lds[DOn + tid];   // logits
      __syncthreads();
      if (tid < 256) lds[768 + tid] = (tid < DOn) ? lds[512 + tid] : -1e30f;
      __syncthreads();
      for (int s = 128; s > 0; s >>= 1) {
        if (tid < s) lds[768 + tid] = fmaxf(lds[768 + tid], lds[768 + tid + s]);
        __syncthreads();
      }
      const float mx = lds[768];
      float e = 0.0f;
      if (tid < 256) {
        e = (tid < DOn) ? __expf(lds[512 + tid] - mx) : 0.0f;
        lds[1024 + tid] = e;
      }
      __syncthreads();
      for (int s = 128; s > 0; s >>= 1) {
        if (tid < s) lds[1024 + tid] += lds[1024 + tid + s];
        __syncthreads();
      }
      const float inv = 1.0f / lds[1024];
      if (tid < DOn) {
        const float p = e * inv;
        xn[(size_t)tid * Bn + b] = p;                        // note(next), transposed
        a.out[((size_t)b * TTn + t) * DOn + tid] = p;        // output
      }
    } else if (((t & 15) == 15) && t != (TTn - 1)) {
      // next step starts a new segment: reset h1 and h2 inputs to dh1/dh2
      int i = (bid - Bn) * NTHR + tid;                       // 0..65535
      xn[(size_t)DOn * Bn + i] = a.sdT[i];
      h2n[i] = a.sdT[(size_t)1024 * Bn + i];
    }
    gbar();
  }
}

extern "C" void kernel_launch(void* const* d_in, const int* in_sizes, int n_in,
                              void* d_out, int out_size, void* d_ws, size_t ws_size,
                              hipStream_t stream) {
  (void)in_sizes; (void)n_in; (void)out_size; (void)ws_size;
  KArgs a;
  a.z   = (const float*)d_in[0];
  a.Wz  = (const float*)d_in[3];  a.bz  = (const float*)d_in[4];
  // d_in[5] = cond_W1 unused (conductor input x0 == 0)
  a.cU1 = (const float*)d_in[6];  a.cb1 = (const float*)d_in[7];
  a.cW2 = (const float*)d_in[8];  a.cU2 = (const float*)d_in[9];  a.cb2 = (const float*)d_in[10];
  a.Wcd = (const float*)d_in[11]; a.bcd = (const float*)d_in[12];
  a.dW1 = (const float*)d_in[13]; a.dU1 = (const float*)d_in[14]; a.db1 = (const float*)d_in[15];
  a.dW2 = (const float*)d_in[16]; a.dU2 = (const float*)d_in[17]; a.db2 = (const float*)d_in[18];
  a.Wp  = (const float*)d_in[19]; a.bp  = (const float*)d_in[20];

  float* ws = (float*)d_ws;
  size_t off = 0;
  a.zT    = ws + off; off += (size_t)Hn * Bn;          // 65536
  a.sT    = ws + off; off += (size_t)NGn * Bn;         // 262144
  a.gbuf  = ws + off; off += (size_t)NGn * Bn;         // 262144
  a.h1cT  = ws + off; off += (size_t)Hn * Bn;
  a.ceT   = ws + off; off += (size_t)Hn * Bn;
  a.sdT   = ws + off; off += (size_t)NGn * Bn;         // dh1|dc1|dh2|dc2
  a.beffT = ws + off; off += (size_t)NGn * Bn;         // permuted cols
  a.xbufA = ws + off; off += (size_t)2 * KAn * Bn;     // [note|h1] x2
  a.h2T   = ws + off; off += (size_t)2 * Hn * Bn;
  a.c1T   = ws + off; off += (size_t)Hn * Bn;
  a.c2T   = ws + off; off += (size_t)Hn * Bn;
  a.h2bk  = ws + off; off += (size_t)Bn * Hn;          // [b][k] for phase C
  a.db1p  = ws + off; off += (size_t)NGn;
  a.db2p  = ws + off; off += (size_t)NGn;
  a.WAp   = ws + off; off += (size_t)KAn * NGn;        // [note|h1] perm
  a.WEp   = ws + off; off += (size_t)Hn * NGn;         // dW1 cond-emb part perm
  a.WBp   = ws + off; off += (size_t)1024 * NGn;       // [dW2|dU2] perm
  a.out   = (float*)d_out;

  hd_kernel<<<dim3(NBLK), dim3(NTHR), 0, stream>>>(a);
}

// Round 3
// 14352.592 us; speedup vs baseline: 6.0343x; 2.5432x over previous
//
#include <hip/hip_runtime.h>
#include <math.h>

// ---- problem dims ----
#define Bn    128     // batch
#define Hn    512     // hidden
#define NGn   2048    // 4H gate width
#define TTn   256     // total decoder steps
#define DOn   176     // output dim
#define KAn   688     // decoder L1 K: 176 (note) + 512 (h1)
#define NBLK  256
#define NTHR  512

struct KArgs {
  const float *z, *Wz, *bz;
  const float *cU1, *cb1, *cW2, *cU2, *cb2;
  const float *Wcd, *bcd;
  const float *dW1, *dU1, *db1, *dW2, *dU2, *db2;
  const float *Wp, *bp;
  float *zT, *sT, *gbuf1, *gbuf2, *h1cT, *ceT, *sdT, *beffT, *xbufA, *h2T, *c1T, *c2T, *h2bk;
  float *WAp, *WEp, *WBp, *db1p, *db2p;
  float *out;
};

// fence-free grid barrier state (self-resetting; g_gen monotonic)
__device__ unsigned g_cnt_l1[16 * 32];   // one counter per 128B to avoid false sharing
__device__ unsigned g_cnt;
__device__ unsigned g_gen;

__device__ __forceinline__ float sigm(float x) { return 1.0f / (1.0f + __expf(-x)); }

// agent-scope (device-coherent, L1/L2-bypassing) load/store for cross-block data
__device__ __forceinline__ float aload(const float* p) {
  return __hip_atomic_load(p, __ATOMIC_RELAXED, __HIP_MEMORY_SCOPE_AGENT);
}
__device__ __forceinline__ void astore(float* p, float v) {
  __hip_atomic_store(p, v, __ATOMIC_RELAXED, __HIP_MEMORY_SCOPE_AGENT);
}

// Fence-free barrier. Safe because:
//  - __syncthreads() drains each wave's vmcnt before s_barrier (compiler-emitted),
//    so the block's agent stores are at the coherence point before arrival.
//  - consumers re-read cross-block data with agent loads (bypass stale L1/L2),
//    so no acquire-invalidate is needed.
__device__ __forceinline__ void gbar() {
  __syncthreads();
  if (threadIdx.x == 0) {
    asm volatile("s_waitcnt vmcnt(0)" ::: "memory");
    unsigned g0 = __hip_atomic_load(&g_gen, __ATOMIC_RELAXED, __HIP_MEMORY_SCOPE_AGENT);
    unsigned p1 = __hip_atomic_fetch_add(&g_cnt_l1[(blockIdx.x >> 4) * 32], 1u,
                                         __ATOMIC_RELAXED, __HIP_MEMORY_SCOPE_AGENT);
    if (p1 == 15u) {
      unsigned p2 = __hip_atomic_fetch_add(&g_cnt, 1u, __ATOMIC_RELAXED, __HIP_MEMORY_SCOPE_AGENT);
      if (p2 == 15u) {
        #pragma unroll
        for (int i = 0; i < 16; i++)
          __hip_atomic_store(&g_cnt_l1[i * 32], 0u, __ATOMIC_RELAXED, __HIP_MEMORY_SCOPE_AGENT);
        __hip_atomic_store(&g_cnt, 0u, __ATOMIC_RELAXED, __HIP_MEMORY_SCOPE_AGENT);
        asm volatile("s_waitcnt vmcnt(0)" ::: "memory");  // resets visible before gen bump
        __hip_atomic_fetch_add(&g_gen, 1u, __ATOMIC_RELAXED, __HIP_MEMORY_SCOPE_AGENT);
      }
    }
    while (__hip_atomic_load(&g_gen, __ATOMIC_RELAXED, __HIP_MEMORY_SCOPE_AGENT) == g0)
      __builtin_amdgcn_s_sleep(1);
  }
  __syncthreads();
}

// stage KR rows x 16 batch of X (row-stride Bn) into xs via agent loads
template<int KR>
__device__ __forceinline__ void stage(float* __restrict__ xs, const float* __restrict__ X,
                                      int krow0, int b0, int tid) {
  #pragma unroll
  for (int r = 0; r < (KR * 16 + NTHR - 1) / NTHR; r++) {
    int i = tid + r * NTHR;
    if ((KR * 16) % NTHR == 0 || i < KR * 16)
      xs[i] = aload(X + (size_t)(krow0 + (i >> 4)) * Bn + b0 + (i & 15));
  }
}

// 8-wave GEMM pass: waves = (col-half ch, k-quarter kq). lane: cl=col 0..31, bh=batch half.
// Weights from global (L2-cached), activations from LDS xs[k][16]. acc[8] accumulates.
template<int KC>
__device__ __forceinline__ void gemmP(const float* __restrict__ Wb, int colbase,
                                      int wid, int lane, const float* __restrict__ xs,
                                      float acc[8]) {
  const int ch = wid & 1, kq = wid >> 1;
  const int cl = lane & 31, bh = lane >> 5;
  const float* wp = Wb + (size_t)(kq * KC) * NGn + colbase + ch * 32 + cl;
  const float* xp = xs + (kq * KC) * 16 + bh * 8;
  #pragma unroll 4
  for (int kk = 0; kk < KC; kk++) {
    const float w = wp[0];
    const float4 x0 = *(const float4*)(xp);
    const float4 x1 = *(const float4*)(xp + 4);
    acc[0] = fmaf(w, x0.x, acc[0]); acc[1] = fmaf(w, x0.y, acc[1]);
    acc[2] = fmaf(w, x0.z, acc[2]); acc[3] = fmaf(w, x0.w, acc[3]);
    acc[4] = fmaf(w, x1.x, acc[4]); acc[5] = fmaf(w, x1.y, acc[5]);
    acc[6] = fmaf(w, x1.z, acc[6]); acc[7] = fmaf(w, x1.w, acc[7]);
    wp += NGn; xp += 16;
  }
}

// store per-wave partials: part[(kq*64 + col)*20 + bl]
__device__ __forceinline__ void pstore(float* __restrict__ part, int wid, int lane,
                                       const float acc[8]) {
  int idx = (((wid >> 1) * 64) + (wid & 1) * 32 + (lane & 31)) * 20 + (lane >> 5) * 8;
  *(float4*)(part + idx)     = make_float4(acc[0], acc[1], acc[2], acc[3]);
  *(float4*)(part + idx + 4) = make_float4(acc[4], acc[5], acc[6], acc[7]);
}

// plain epilogue: out[col][b] = f(sum4 + bias[col]); MODE 0 = tanh, 1 = identity
template<int MODE>
__device__ __forceinline__ void epi_plain(const float* bias, float* out,
                                          int colbase, int b0, int tid,
                                          const float* __restrict__ part) {
  #pragma unroll
  for (int rep = 0; rep < 2; rep++) {
    int e = tid + rep * NTHR;       // 0..1023
    int cl = e >> 4, bl = e & 15;
    float s = part[cl * 20 + bl] + part[(64 + cl) * 20 + bl]
            + part[(128 + cl) * 20 + bl] + part[(192 + cl) * 20 + bl];
    if (bias) s += bias[colbase + cl];
    if (MODE == 0) s = tanhf(s);
    astore(out + (size_t)(colbase + cl) * Bn + b0 + bl, s);
  }
}

// decoder L1 LSTM epilogue (permuted cols: cl = h*4+g)
__device__ __forceinline__ void epi_lstmA(const KArgs& a, int ht, int b0, int tid,
                                          const float* __restrict__ part, bool rst, float* xn) {
  if (tid < 256) {
    int h = tid >> 4, bl = tid & 15;
    int hid = ht * 16 + h, b = b0 + bl;
    float g4[4];
    #pragma unroll
    for (int g = 0; g < 4; g++) {
      int cl = h * 4 + g;
      float s = part[cl * 20 + bl] + part[(64 + cl) * 20 + bl]
              + part[(128 + cl) * 20 + bl] + part[(192 + cl) * 20 + bl];
      g4[g] = s + a.beffT[(size_t)(ht * 64 + cl) * Bn + b];
    }
    float cprev = rst ? a.sdT[(size_t)(Hn + hid) * Bn + b] : a.c1T[(size_t)hid * Bn + b];
    float c = sigm(g4[1]) * cprev + sigm(g4[0]) * tanhf(g4[2]);
    a.c1T[(size_t)hid * Bn + b] = c;                      // block-private, cached
    astore(xn + (size_t)(DOn + hid) * Bn + b, sigm(g4[3]) * tanhf(c));
  }
}

// decoder L2 LSTM epilogue
__device__ __forceinline__ void epi_lstmB(const KArgs& a, int ht, int b0, int tid,
                                          const float* __restrict__ part, bool rst, float* h2n) {
  if (tid < 256) {
    int h = tid >> 4, bl = tid & 15;
    int hid = ht * 16 + h, b = b0 + bl;
    float g4[4];
    #pragma unroll
    for (int g = 0; g < 4; g++) {
      int cl = h * 4 + g;
      float s = part[cl * 20 + bl] + part[(64 + cl) * 20 + bl]
              + part[(128 + cl) * 20 + bl] + part[(192 + cl) * 20 + bl];
      g4[g] = s + a.db2p[ht * 64 + cl];
    }
    float cprev = rst ? a.sdT[(size_t)(1536 + hid) * Bn + b] : a.c2T[(size_t)hid * Bn + b];
    float c = sigm(g4[1]) * cprev + sigm(g4[0]) * tanhf(g4[2]);
    a.c2T[(size_t)hid * Bn + b] = c;                      // block-private, cached
    float h2 = sigm(g4[3]) * tanhf(c);
    astore(h2n + (size_t)hid * Bn + b, h2);
    astore(a.h2bk + (size_t)b * Hn + hid, h2);            // [b][k] copy for phase C
  }
}

// conductor LSTM nonlinearity from plain-layout raw gates
__device__ __forceinline__ void cond_nl(const KArgs& a, const float* gb, const float* cbias,
                                        const float* cin, float* hout, int bid, int tid) {
  int i = bid * NTHR + tid;
  if (i < Hn * Bn) {
    int hid = i >> 7, b = i & 127;
    float gi = gb[(size_t)hid * Bn + b]            + cbias[hid];
    float gf = gb[(size_t)(Hn + hid) * Bn + b]     + cbias[Hn + hid];
    float gg = gb[(size_t)(2 * Hn + hid) * Bn + b] + cbias[2 * Hn + hid];
    float go = gb[(size_t)(3 * Hn + hid) * Bn + b] + cbias[3 * Hn + hid];
    float cprev = cin[(size_t)hid * Bn + b];
    float c = sigm(gf) * cprev + sigm(gi) * tanhf(gg);
    astore(hout + (size_t)hid * Bn + b, sigm(go) * tanhf(c));
  }
}

__global__ void __launch_bounds__(NTHR, 2)
hd_kernel(KArgs a) {
  __shared__ float xs[8192];     // 32 KB activation stage
  __shared__ float part[5120];   // 20.5 KB partial buffer [kq][64 col][pad 20]
  const int bid = blockIdx.x, tid = threadIdx.x;
  const int wid = tid >> 6, lane = tid & 63;
  // XCD swizzle: bid%8 = XCD; col-tiles grouped so each XCD's weight slice stays L2-resident
  const int ht = (bid & 7) * 4 + ((bid >> 3) & 3);   // col-tile 0..31 (16 hidden x 4 gates)
  const int bt = bid >> 5;                           // batch tile 0..7
  const int colbase = ht * 64, b0 = bt * 16;

  // ---- P-1: transpose z, zero note rows, permute weights/biases (agent stores) ----
  {
    int i = bid * NTHR + tid;                        // 0..131071
    if (i < Hn * Bn) { int zb = i >> 9, zk = i & 511; astore(a.zT + (size_t)zk * Bn + zb, a.z[i]); }
    int i2 = i - Hn * Bn;
    if (i2 >= 0 && i2 < DOn * Bn) astore(a.xbufA + i2, 0.0f);
    if (i < NGn) {
      int g = i & 3, hid = ((i >> 6) << 4) | ((i >> 2) & 15);
      int col = g * Hn + hid;
      astore(a.db1p + i, a.db1[col]);
      astore(a.db2p + i, a.db2[col]);
    }
    const int NA = KAn * NGn;
    for (int j = i; j < NA; j += NBLK * NTHR) {
      int k = j >> 11, pc = j & 2047;
      int g = pc & 3, hid = ((pc >> 6) << 4) | ((pc >> 2) & 15);
      int col = g * Hn + hid;
      astore(a.WAp + j, (k < DOn) ? a.dW1[(size_t)k * NGn + col]
                                  : a.dU1[(size_t)(k - DOn) * NGn + col]);
    }
    const int NE = Hn * NGn;
    for (int j = i; j < NE; j += NBLK * NTHR) {
      int k = j >> 11, pc = j & 2047;
      int g = pc & 3, hid = ((pc >> 6) << 4) | ((pc >> 2) & 15);
      astore(a.WEp + j, a.dW1[(size_t)(DOn + k) * NGn + g * Hn + hid]);
    }
    const int NB = 1024 * NGn;
    for (int j = i; j < NB; j += NBLK * NTHR) {
      int k = j >> 11, pc = j & 2047;
      int g = pc & 3, hid = ((pc >> 6) << 4) | ((pc >> 2) & 15);
      int col = g * Hn + hid;
      astore(a.WBp + j, (k < Hn) ? a.dW2[(size_t)k * NGn + col]
                                 : a.dU2[(size_t)(k - Hn) * NGn + col]);
    }
  }
  gbar();
  // ---- P0: sT = tanh(z @ Wz + bz) ----
  {
    float acc[8] = {0,0,0,0,0,0,0,0};
    stage<512>(xs, a.zT, 0, b0, tid); __syncthreads();
    gemmP<128>(a.Wz, colbase, wid, lane, xs, acc);
    pstore(part, wid, lane, acc); __syncthreads();
    epi_plain<0>(a.bz, a.sT, colbase, b0, tid, part);
  }
  gbar();
  // ---- P1: conductor L1 raw gates = ch1 @ cU1 -> gbuf1 ----
  {
    float acc[8] = {0,0,0,0,0,0,0,0};
    stage<512>(xs, a.sT, 0, b0, tid); __syncthreads();
    gemmP<128>(a.cU1, colbase, wid, lane, xs, acc);
    pstore(part, wid, lane, acc); __syncthreads();
    epi_plain<1>(nullptr, a.gbuf1, colbase, b0, tid, part);
  }
  gbar();
  cond_nl(a, a.gbuf1, a.cb1, a.sT + (size_t)Hn * Bn, a.h1cT, bid, tid);
  gbar();
  // ---- P2: conductor L2 raw gates = h1c @ cW2 + ch2 @ cU2 -> gbuf2 ----
  {
    float acc[8] = {0,0,0,0,0,0,0,0};
    stage<512>(xs, a.h1cT, 0, b0, tid); __syncthreads();
    gemmP<128>(a.cW2, colbase, wid, lane, xs, acc); __syncthreads();
    stage<512>(xs, a.sT + (size_t)1024 * Bn, 0, b0, tid); __syncthreads();
    gemmP<128>(a.cU2, colbase, wid, lane, xs, acc);
    pstore(part, wid, lane, acc); __syncthreads();
    epi_plain<1>(nullptr, a.gbuf2, colbase, b0, tid, part);
  }
  gbar();
  cond_nl(a, a.gbuf2, a.cb2, a.sT + (size_t)1536 * Bn, a.ceT, bid, tid);
  gbar();
  // ---- P3: sdT = tanh(ce @ Wcd + bcd); beffT = db1p + ce @ WEp ----
  {
    float acc[8] = {0,0,0,0,0,0,0,0};
    stage<512>(xs, a.ceT, 0, b0, tid); __syncthreads();
    gemmP<128>(a.Wcd, colbase, wid, lane, xs, acc);
    pstore(part, wid, lane, acc); __syncthreads();
    epi_plain<0>(a.bcd, a.sdT, colbase, b0, tid, part);
    __syncthreads();
    float acc2[8] = {0,0,0,0,0,0,0,0};
    gemmP<128>(a.WEp, colbase, wid, lane, xs, acc2);   // xs still holds ceT
    pstore(part, wid, lane, acc2); __syncthreads();
    epi_plain<1>(a.db1p, a.beffT, colbase, b0, tid, part);
  }
  gbar();
  // ---- P4: state init: dh1 -> xbufA[0] h1 rows, dh2 -> h2T[0] ----
  {
    int i = bid * NTHR + tid;
    if (i < Hn * Bn) {
      astore(a.xbufA + (size_t)DOn * Bn + i, a.sdT[i]);
      astore(a.h2T + i, a.sdT[(size_t)1024 * Bn + i]);
    }
  }
  gbar();

  // ---- main loop ----
  for (int t = 0; t < TTn; t++) {
    const int cur = t & 1;
    float* xc  = a.xbufA + (size_t)cur * (KAn * Bn);
    float* xn  = a.xbufA + (size_t)(cur ^ 1) * (KAn * Bn);
    float* h2c = a.h2T + (size_t)cur * (Hn * Bn);
    float* h2n = a.h2T + (size_t)(cur ^ 1) * (Hn * Bn);
    const bool rst = (t & 15) == 0;

    // phase A: decoder L1 (K=688 over 2 passes)
    {
      float acc[8] = {0,0,0,0,0,0,0,0};
      stage<344>(xs, xc, 0, b0, tid); __syncthreads();
      gemmP<86>(a.WAp, colbase, wid, lane, xs, acc); __syncthreads();
      stage<344>(xs, xc, 344, b0, tid); __syncthreads();
      gemmP<86>(a.WAp + (size_t)344 * NGn, colbase, wid, lane, xs, acc);
      pstore(part, wid, lane, acc); __syncthreads();
      epi_lstmA(a, ht, b0, tid, part, rst, xn);
    }
    gbar();

    // phase B: decoder L2 (K=1024 over 2 passes: h1' then h2)
    {
      float acc[8] = {0,0,0,0,0,0,0,0};
      stage<512>(xs, xn + (size_t)DOn * Bn, 0, b0, tid); __syncthreads();
      gemmP<128>(a.WBp, colbase, wid, lane, xs, acc); __syncthreads();
      stage<512>(xs, h2c, 0, b0, tid); __syncthreads();
      gemmP<128>(a.WBp + (size_t)Hn * NGn, colbase, wid, lane, xs, acc);
      pstore(part, wid, lane, acc); __syncthreads();
      epi_lstmB(a, ht, b0, tid, part, rst, h2n);
    }
    gbar();

    // phase C: projection + softmax (blocks 0..127); segment-reset copies (blocks 128+)
    if (bid < Bn) {
      const int b = bid;
      xs[tid] = aload(a.h2bk + (size_t)b * Hn + tid);    // stage h2 row (512 floats)
      __syncthreads();
      const int o = tid & 255, kh = tid >> 8;
      float acc = 0.0f;
      if (o < DOn) {
        const float* wr = a.Wp + (size_t)(kh * 256) * DOn + o;
        if (kh == 0) acc = a.bp[o];
        for (int k = 0; k < 256; k++)
          acc = fmaf(xs[kh * 256 + k], wr[(size_t)k * DOn], acc);
      }
      if (o < 256) part[kh * 256 + o] = acc;
      __syncthreads();
      float lg = 0.0f;
      if (tid < DOn) lg = part[tid] + part[256 + tid];
      if (tid < 256) part[512 + tid] = (tid < DOn) ? lg : -1e30f;
      __syncthreads();
      for (int s = 128; s > 0; s >>= 1) {
        if (tid < s) part[512 + tid] = fmaxf(part[512 + tid], part[512 + tid + s]);
        __syncthreads();
      }
      const float mx = part[512];
      float e = 0.0f;
      if (tid < 256) {
        e = (tid < DOn) ? __expf(lg - mx) : 0.0f;
        part[768 + tid] = e;
      }
      __syncthreads();
      for (int s = 128; s > 0; s >>= 1) {
        if (tid < s) part[768 + tid] += part[768 + tid + s];
        __syncthreads();
      }
      const float inv = 1.0f / part[768];
      if (tid < DOn) {
        const float p = e * inv;
        astore(xn + (size_t)tid * Bn + b, p);            // note(next), transposed
        a.out[((size_t)b * TTn + t) * DOn + tid] = p;    // output (host-visible)
      }
    } else if (((t & 15) == 15) && t != (TTn - 1)) {
      // next step starts a new segment: reset h1/h2 inputs to dh1/dh2
      int i = (bid - Bn) * NTHR + tid;                   // 0..65535
      astore(xn + (size_t)DOn * Bn + i, a.sdT[i]);
      astore(h2n + i, a.sdT[(size_t)1024 * Bn + i]);
    }
    gbar();
  }
}

extern "C" void kernel_launch(void* const* d_in, const int* in_sizes, int n_in,
                              void* d_out, int out_size, void* d_ws, size_t ws_size,
                              hipStream_t stream) {
  (void)in_sizes; (void)n_in; (void)out_size; (void)ws_size;
  KArgs a;
  a.z   = (const float*)d_in[0];
  a.Wz  = (const float*)d_in[3];  a.bz  = (const float*)d_in[4];
  // d_in[5] = cond_W1 unused (conductor input x0 == 0)
  a.cU1 = (const float*)d_in[6];  a.cb1 = (const float*)d_in[7];
  a.cW2 = (const float*)d_in[8];  a.cU2 = (const float*)d_in[9];  a.cb2 = (const float*)d_in[10];
  a.Wcd = (const float*)d_in[11]; a.bcd = (const float*)d_in[12];
  a.dW1 = (const float*)d_in[13]; a.dU1 = (const float*)d_in[14]; a.db1 = (const float*)d_in[15];
  a.dW2 = (const float*)d_in[16]; a.dU2 = (const float*)d_in[17]; a.db2 = (const float*)d_in[18];
  a.Wp  = (const float*)d_in[19]; a.bp  = (const float*)d_in[20];

  float* ws = (float*)d_ws;
  size_t off = 0;
  a.zT    = ws + off; off += (size_t)Hn * Bn;
  a.sT    = ws + off; off += (size_t)NGn * Bn;
  a.gbuf1 = ws + off; off += (size_t)NGn * Bn;
  a.gbuf2 = ws + off; off += (size_t)NGn * Bn;
  a.h1cT  = ws + off; off += (size_t)Hn * Bn;
  a.ceT   = ws + off; off += (size_t)Hn * Bn;
  a.sdT   = ws + off; off += (size_t)NGn * Bn;         // dh1|dc1|dh2|dc2
  a.beffT = ws + off; off += (size_t)NGn * Bn;         // permuted cols
  a.xbufA = ws + off; off += (size_t)2 * KAn * Bn;     // [note|h1] x2
  a.h2T   = ws + off; off += (size_t)2 * Hn * Bn;
  a.c1T   = ws + off; off += (size_t)Hn * Bn;
  a.c2T   = ws + off; off += (size_t)Hn * Bn;
  a.h2bk  = ws + off; off += (size_t)Bn * Hn;          // [b][k] for phase C
  a.db1p  = ws + off; off += (size_t)NGn;
  a.db2p  = ws + off; off += (size_t)NGn;
  a.WAp   = ws + off; off += (size_t)KAn * NGn;        // [note|h1] permuted
  a.WEp   = ws + off; off += (size_t)Hn * NGn;         // dW1 cond-emb part permuted
  a.WBp   = ws + off; off += (size_t)1024 * NGn;       // [dW2|dU2] permuted
  a.out   = (float*)d_out;

  hd_kernel<<<dim3(NBLK), dim3(NTHR), 0, stream>>>(a);
}

// Round 4
// 10552.927 us; speedup vs baseline: 8.2070x; 1.3601x over previous
//
#include <hip/hip_runtime.h>
#include <math.h>

// ---- problem dims ----
#define Bn    128     // batch
#define Hn    512     // hidden
#define NGn   2048    // 4H gate width
#define TTn   256     // total decoder steps
#define DOn   176     // output dim
#define KAn   688     // decoder L1 K: 176 (note) + 512 (h1)
#define NBLK  256
#define NTHR  512

struct KArgs {
  const float *z, *Wz, *bz;
  const float *cU1, *cb1, *cW2, *cU2, *cb2;
  const float *Wcd, *bcd;
  const float *dW1, *dU1, *db1, *dW2, *dU2, *db2;
  const float *Wp, *bp;
  float *zT, *sT, *gbuf1, *gbuf2, *h1cT, *ceT, *sdT, *beffT, *xbufA, *h2T, *c1T, *c2T, *h2bk;
  float *WAp, *WEp, *WBp, *db1p, *db2p;
  float *out;
};

// global barrier state (preamble only; self-resetting, gen monotonic)
__device__ unsigned g_cnt_l1[16 * 32];
__device__ unsigned g_cnt;
__device__ unsigned g_gen;
// pod barrier state: pod p uses its own cache line
__device__ unsigned pod_cnt[8 * 64];
__device__ unsigned pod_gen[8 * 64];

__device__ __forceinline__ float sigm(float x) { return 1.0f / (1.0f + __expf(-x)); }

// device-coherent (L3) load/store for cross-block data
__device__ __forceinline__ float aload(const float* p) {
  return __hip_atomic_load(p, __ATOMIC_RELAXED, __HIP_MEMORY_SCOPE_AGENT);
}
__device__ __forceinline__ void astore(float* p, float v) {
  __hip_atomic_store(p, v, __ATOMIC_RELAXED, __HIP_MEMORY_SCOPE_AGENT);
}

// global barrier (preamble). __syncthreads drains vmcnt per-wave before arrive.
__device__ __forceinline__ void gbar() {
  __syncthreads();
  if (threadIdx.x == 0) {
    unsigned g0 = __hip_atomic_load(&g_gen, __ATOMIC_RELAXED, __HIP_MEMORY_SCOPE_AGENT);
    unsigned p1 = __hip_atomic_fetch_add(&g_cnt_l1[(blockIdx.x >> 4) * 32], 1u,
                                         __ATOMIC_RELAXED, __HIP_MEMORY_SCOPE_AGENT);
    if (p1 == 15u) {
      unsigned p2 = __hip_atomic_fetch_add(&g_cnt, 1u, __ATOMIC_RELAXED, __HIP_MEMORY_SCOPE_AGENT);
      if (p2 == 15u) {
        #pragma unroll
        for (int i = 0; i < 16; i++)
          __hip_atomic_store(&g_cnt_l1[i * 32], 0u, __ATOMIC_RELAXED, __HIP_MEMORY_SCOPE_AGENT);
        __hip_atomic_store(&g_cnt, 0u, __ATOMIC_RELAXED, __HIP_MEMORY_SCOPE_AGENT);
        asm volatile("s_waitcnt vmcnt(0)" ::: "memory");
        __hip_atomic_fetch_add(&g_gen, 1u, __ATOMIC_RELAXED, __HIP_MEMORY_SCOPE_AGENT);
      }
    }
    while (__hip_atomic_load(&g_gen, __ATOMIC_RELAXED, __HIP_MEMORY_SCOPE_AGENT) == g0)
      __builtin_amdgcn_s_sleep(1);
  }
  __syncthreads();
}

// pod barrier: 32 blocks, tight spin, per-pod cache line
__device__ __forceinline__ void pbar(int pod) {
  __syncthreads();
  if (threadIdx.x == 0) {
    unsigned* cnt = &pod_cnt[pod * 64];
    unsigned* gen = &pod_gen[pod * 64];
    unsigned g0 = __hip_atomic_load(gen, __ATOMIC_RELAXED, __HIP_MEMORY_SCOPE_AGENT);
    unsigned p = __hip_atomic_fetch_add(cnt, 1u, __ATOMIC_RELAXED, __HIP_MEMORY_SCOPE_AGENT);
    if (p == 31u) {
      __hip_atomic_store(cnt, 0u, __ATOMIC_RELAXED, __HIP_MEMORY_SCOPE_AGENT);
      asm volatile("s_waitcnt vmcnt(0)" ::: "memory");   // cnt reset visible before release
      __hip_atomic_fetch_add(gen, 1u, __ATOMIC_RELAXED, __HIP_MEMORY_SCOPE_AGENT);
    } else {
      while (__hip_atomic_load(gen, __ATOMIC_RELAXED, __HIP_MEMORY_SCOPE_AGENT) == g0) { }
    }
  }
  __syncthreads();
}

// stage nrows x 16 batch of X (row stride Bn) into xs via L3 loads
__device__ __forceinline__ void stageN(float* __restrict__ xs, const float* __restrict__ X,
                                       int nrows, int b0, int tid) {
  for (int i = tid; i < nrows * 16; i += NTHR)
    xs[i] = aload(X + (size_t)(i >> 4) * Bn + b0 + (i & 15));
}

// GEMM pass: 8 waves = k-split. thread = 4 cols (cg) x 4 batches (bg), acc[c*4+b].
// per k: 1 float4 weight load + 1 float4 LDS read + 16 FMA.
template<int KC>
__device__ __forceinline__ void gemm16(const float* __restrict__ Wb, int colbase,
                                       int kq, int cg, int bg,
                                       const float* __restrict__ xsrc, float acc[16]) {
  const float* wp = Wb + (size_t)(kq * KC) * NGn + colbase + cg * 4;
  const float* xp = xsrc + (kq * KC) * 16 + bg * 4;
  #pragma unroll 2
  for (int kk = 0; kk < KC; kk++) {
    const float4 w4 = *(const float4*)(wp);
    const float4 x4 = *(const float4*)(xp);
    acc[0]  = fmaf(w4.x, x4.x, acc[0]);  acc[1]  = fmaf(w4.x, x4.y, acc[1]);
    acc[2]  = fmaf(w4.x, x4.z, acc[2]);  acc[3]  = fmaf(w4.x, x4.w, acc[3]);
    acc[4]  = fmaf(w4.y, x4.x, acc[4]);  acc[5]  = fmaf(w4.y, x4.y, acc[5]);
    acc[6]  = fmaf(w4.y, x4.z, acc[6]);  acc[7]  = fmaf(w4.y, x4.w, acc[7]);
    acc[8]  = fmaf(w4.z, x4.x, acc[8]);  acc[9]  = fmaf(w4.z, x4.y, acc[9]);
    acc[10] = fmaf(w4.z, x4.z, acc[10]); acc[11] = fmaf(w4.z, x4.w, acc[11]);
    acc[12] = fmaf(w4.w, x4.x, acc[12]); acc[13] = fmaf(w4.w, x4.y, acc[13]);
    acc[14] = fmaf(w4.w, x4.z, acc[14]); acc[15] = fmaf(w4.w, x4.w, acc[15]);
    wp += NGn; xp += 16;
  }
}

// store per-wave partials: part[(kq*64 + col)*17 + b]
__device__ __forceinline__ void pstore(float* __restrict__ part, int kq, int cg, int bg,
                                       const float acc[16]) {
  #pragma unroll
  for (int c = 0; c < 4; c++) {
    float* p = part + (size_t)(kq * 64 + cg * 4 + c) * 17 + bg * 4;
    *(float4*)p = make_float4(acc[c*4], acc[c*4+1], acc[c*4+2], acc[c*4+3]);
  }
}

// plain epilogue: out[col][b] = f(sum8 + bias[col]); MODE 0 = tanh, 1 = identity
template<int MODE>
__device__ __forceinline__ void epi_plain(const float* bias, float* out,
                                          int colbase, int b0, int tid,
                                          const float* __restrict__ part) {
  #pragma unroll
  for (int rep = 0; rep < 2; rep++) {
    int e = tid + rep * NTHR;       // 0..1023
    int cl = e >> 4, bl = e & 15;
    float s = 0.0f;
    #pragma unroll
    for (int w = 0; w < 8; w++) s += part[(w * 64 + cl) * 17 + bl];
    if (bias) s += bias[colbase + cl];
    if (MODE == 0) s = tanhf(s);
    astore(out + (size_t)(colbase + cl) * Bn + b0 + bl, s);
  }
}

// decoder L1 LSTM epilogue (permuted cols: cl = h*4+g)
__device__ __forceinline__ void epi_lstmA(const KArgs& a, int ht, int b0, int tid,
                                          const float* __restrict__ part, bool rst, float* xn) {
  if (tid < 256) {
    int h = tid >> 4, bl = tid & 15;
    int hid = ht * 16 + h, b = b0 + bl;
    float g4[4];
    #pragma unroll
    for (int g = 0; g < 4; g++) {
      int cl = h * 4 + g;
      float s = 0.0f;
      #pragma unroll
      for (int w = 0; w < 8; w++) s += part[(w * 64 + cl) * 17 + bl];
      g4[g] = s + a.beffT[(size_t)(ht * 64 + cl) * Bn + b];
    }
    float cprev = rst ? a.sdT[(size_t)(Hn + hid) * Bn + b] : a.c1T[(size_t)hid * Bn + b];
    float c = sigm(g4[1]) * cprev + sigm(g4[0]) * tanhf(g4[2]);
    a.c1T[(size_t)hid * Bn + b] = c;                      // block-private
    astore(xn + (size_t)(DOn + hid) * Bn + b, sigm(g4[3]) * tanhf(c));
  }
}

// decoder L2 LSTM epilogue
__device__ __forceinline__ void epi_lstmB(const KArgs& a, int ht, int b0, int tid,
                                          const float* __restrict__ part, bool rst, float* h2n) {
  if (tid < 256) {
    int h = tid >> 4, bl = tid & 15;
    int hid = ht * 16 + h, b = b0 + bl;
    float g4[4];
    #pragma unroll
    for (int g = 0; g < 4; g++) {
      int cl = h * 4 + g;
      float s = 0.0f;
      #pragma unroll
      for (int w = 0; w < 8; w++) s += part[(w * 64 + cl) * 17 + bl];
      g4[g] = s + a.db2p[ht * 64 + cl];
    }
    float cprev = rst ? a.sdT[(size_t)(1536 + hid) * Bn + b] : a.c2T[(size_t)hid * Bn + b];
    float c = sigm(g4[1]) * cprev + sigm(g4[0]) * tanhf(g4[2]);
    a.c2T[(size_t)hid * Bn + b] = c;                      // block-private
    float h2 = sigm(g4[3]) * tanhf(c);
    astore(h2n + (size_t)hid * Bn + b, h2);
    astore(a.h2bk + (size_t)b * Hn + hid, h2);            // [b][k] for phase C
  }
}

// conductor LSTM nonlinearity (preamble)
__device__ __forceinline__ void cond_nl(const KArgs& a, const float* gb, const float* cbias,
                                        const float* cin, float* hout, int bid, int tid) {
  int i = bid * NTHR + tid;
  if (i < Hn * Bn) {
    int hid = i >> 7, b = i & 127;
    float gi = aload(gb + (size_t)hid * Bn + b)            + cbias[hid];
    float gf = aload(gb + (size_t)(Hn + hid) * Bn + b)     + cbias[Hn + hid];
    float gg = aload(gb + (size_t)(2 * Hn + hid) * Bn + b) + cbias[2 * Hn + hid];
    float go = aload(gb + (size_t)(3 * Hn + hid) * Bn + b) + cbias[3 * Hn + hid];
    float cprev = aload(cin + (size_t)hid * Bn + b);
    float c = sigm(gf) * cprev + sigm(gi) * tanhf(gg);
    astore(hout + (size_t)hid * Bn + b, sigm(go) * tanhf(c));
  }
}

__global__ void __launch_bounds__(NTHR, 2)
hd_kernel(KArgs a) {
  __shared__ float xs[16384];    // 64 KB activation stage (max K=1024 x 16)
  __shared__ float part[8704];   // 34.8 KB partials [8 kq][64 col][17 pad]
  const int bid = blockIdx.x, tid = threadIdx.x;
  const int kq = tid >> 6, lane = tid & 63;
  const int cg = lane & 15, bg = lane >> 4;
  const int r = bid & 31, pod = bid >> 5;            // pod = batch tile of 16
  const int ht = (r & 7) * 4 + (r >> 3);             // col-tile 0..31; same XCD per ht
  const int colbase = ht * 64, b0 = pod * 16;

  // ---- P-1: transpose z, zero note rows, permute weights/biases ----
  {
    int i = bid * NTHR + tid;
    if (i < Hn * Bn) { int zb = i >> 9, zk = i & 511; astore(a.zT + (size_t)zk * Bn + zb, a.z[i]); }
    int i2 = i - Hn * Bn;
    if (i2 >= 0 && i2 < DOn * Bn) astore(a.xbufA + i2, 0.0f);
    if (i < NGn) {
      int g = i & 3, hid = ((i >> 6) << 4) | ((i >> 2) & 15);
      int col = g * Hn + hid;
      astore(a.db1p + i, a.db1[col]);
      astore(a.db2p + i, a.db2[col]);
    }
    const int NA = KAn * NGn;
    for (int j = i; j < NA; j += NBLK * NTHR) {
      int k = j >> 11, pc = j & 2047;
      int g = pc & 3, hid = ((pc >> 6) << 4) | ((pc >> 2) & 15);
      int col = g * Hn + hid;
      astore(a.WAp + j, (k < DOn) ? a.dW1[(size_t)k * NGn + col]
                                  : a.dU1[(size_t)(k - DOn) * NGn + col]);
    }
    const int NE = Hn * NGn;
    for (int j = i; j < NE; j += NBLK * NTHR) {
      int k = j >> 11, pc = j & 2047;
      int g = pc & 3, hid = ((pc >> 6) << 4) | ((pc >> 2) & 15);
      astore(a.WEp + j, a.dW1[(size_t)(DOn + k) * NGn + g * Hn + hid]);
    }
    const int NB = 1024 * NGn;
    for (int j = i; j < NB; j += NBLK * NTHR) {
      int k = j >> 11, pc = j & 2047;
      int g = pc & 3, hid = ((pc >> 6) << 4) | ((pc >> 2) & 15);
      int col = g * Hn + hid;
      astore(a.WBp + j, (k < Hn) ? a.dW2[(size_t)k * NGn + col]
                                 : a.dU2[(size_t)(k - Hn) * NGn + col]);
    }
  }
  gbar();
  // ---- P0: sT = tanh(z @ Wz + bz) ----
  {
    float acc[16] = {0,0,0,0,0,0,0,0,0,0,0,0,0,0,0,0};
    stageN(xs, a.zT, 512, b0, tid); __syncthreads();
    gemm16<64>(a.Wz, colbase, kq, cg, bg, xs, acc);
    pstore(part, kq, cg, bg, acc); __syncthreads();
    epi_plain<0>(a.bz, a.sT, colbase, b0, tid, part);
  }
  gbar();
  // ---- P1: conductor L1 raw gates = ch1 @ cU1 -> gbuf1 ----
  {
    float acc[16] = {0,0,0,0,0,0,0,0,0,0,0,0,0,0,0,0};
    stageN(xs, a.sT, 512, b0, tid); __syncthreads();
    gemm16<64>(a.cU1, colbase, kq, cg, bg, xs, acc);
    pstore(part, kq, cg, bg, acc); __syncthreads();
    epi_plain<1>(nullptr, a.gbuf1, colbase, b0, tid, part);
  }
  gbar();
  cond_nl(a, a.gbuf1, a.cb1, a.sT + (size_t)Hn * Bn, a.h1cT, bid, tid);
  gbar();
  // ---- P2: conductor L2 raw gates = h1c @ cW2 + ch2 @ cU2 -> gbuf2 ----
  {
    float acc[16] = {0,0,0,0,0,0,0,0,0,0,0,0,0,0,0,0};
    stageN(xs, a.h1cT, 512, b0, tid);
    stageN(xs + 8192, a.sT + (size_t)1024 * Bn, 512, b0, tid);
    __syncthreads();
    gemm16<64>(a.cW2, colbase, kq, cg, bg, xs, acc);
    gemm16<64>(a.cU2, colbase, kq, cg, bg, xs + 8192, acc);
    pstore(part, kq, cg, bg, acc); __syncthreads();
    epi_plain<1>(nullptr, a.gbuf2, colbase, b0, tid, part);
  }
  gbar();
  cond_nl(a, a.gbuf2, a.cb2, a.sT + (size_t)1536 * Bn, a.ceT, bid, tid);
  gbar();
  // ---- P3: sdT = tanh(ce @ Wcd + bcd); beffT = db1p + ce @ WEp ----
  {
    float acc[16] = {0,0,0,0,0,0,0,0,0,0,0,0,0,0,0,0};
    stageN(xs, a.ceT, 512, b0, tid); __syncthreads();
    gemm16<64>(a.Wcd, colbase, kq, cg, bg, xs, acc);
    pstore(part, kq, cg, bg, acc); __syncthreads();
    epi_plain<0>(a.bcd, a.sdT, colbase, b0, tid, part);
    __syncthreads();
    float acc2[16] = {0,0,0,0,0,0,0,0,0,0,0,0,0,0,0,0};
    gemm16<64>(a.WEp, colbase, kq, cg, bg, xs, acc2);
    pstore(part, kq, cg, bg, acc2); __syncthreads();
    epi_plain<1>(a.db1p, a.beffT, colbase, b0, tid, part);
  }
  gbar();
  // ---- P4: state init: dh1 -> xbufA[0] h1 rows, dh2 -> h2T[0] ----
  {
    int i = bid * NTHR + tid;
    if (i < Hn * Bn) {
      astore(a.xbufA + (size_t)DOn * Bn + i, aload(a.sdT + i));
      astore(a.h2T + i, aload(a.sdT + (size_t)1024 * Bn + i));
    }
  }
  gbar();

  // ---- main loop: pod-local sync only ----
  for (int t = 0; t < TTn; t++) {
    const int cur = t & 1;
    float* xc  = a.xbufA + (size_t)cur * (KAn * Bn);
    float* xn  = a.xbufA + (size_t)(cur ^ 1) * (KAn * Bn);
    float* h2c = a.h2T + (size_t)cur * (Hn * Bn);
    float* h2n = a.h2T + (size_t)(cur ^ 1) * (Hn * Bn);
    const bool rst = (t & 15) == 0;

    // phase A: decoder L1 (K=688 single pass)
    {
      float acc[16] = {0,0,0,0,0,0,0,0,0,0,0,0,0,0,0,0};
      stageN(xs, xc, KAn, b0, tid); __syncthreads();
      gemm16<86>(a.WAp, colbase, kq, cg, bg, xs, acc);
      pstore(part, kq, cg, bg, acc); __syncthreads();
      epi_lstmA(a, ht, b0, tid, part, rst, xn);
    }
    pbar(pod);

    // phase B: decoder L2 (K=1024 single pass: [h1' | h2])
    {
      float acc[16] = {0,0,0,0,0,0,0,0,0,0,0,0,0,0,0,0};
      stageN(xs, xn + (size_t)DOn * Bn, 512, b0, tid);
      stageN(xs + 8192, h2c, 512, b0, tid);
      __syncthreads();
      gemm16<128>(a.WBp, colbase, kq, cg, bg, xs, acc);
      pstore(part, kq, cg, bg, acc); __syncthreads();
      epi_lstmB(a, ht, b0, tid, part, rst, h2n);
    }
    pbar(pod);

    // phase C: projection + softmax on 16 blocks; segment-reset copies on the rest
    if (ht < 16) {
      const int b = b0 + ht;
      xs[tid] = aload(a.h2bk + (size_t)b * Hn + tid);    // 512 floats
      __syncthreads();
      const int o = tid & 255, kh = tid >> 8;
      float acc = 0.0f;
      if (o < DOn) {
        const float* wr = a.Wp + (size_t)(kh * 256) * DOn + o;
        if (kh == 0) acc = a.bp[o];
        for (int k = 0; k < 256; k++)
          acc = fmaf(xs[kh * 256 + k], wr[(size_t)k * DOn], acc);
      }
      if (o < 256) part[kh * 256 + o] = acc;
      __syncthreads();
      float lg = 0.0f;
      if (tid < DOn) lg = part[tid] + part[256 + tid];
      if (tid < 256) part[512 + tid] = (tid < DOn) ? lg : -1e30f;
      __syncthreads();
      for (int s = 128; s > 0; s >>= 1) {
        if (tid < s) part[512 + tid] = fmaxf(part[512 + tid], part[512 + tid + s]);
        __syncthreads();
      }
      const float mx = part[512];
      float e = 0.0f;
      if (tid < 256) {
        e = (tid < DOn) ? __expf(lg - mx) : 0.0f;
        part[768 + tid] = e;
      }
      __syncthreads();
      for (int s = 128; s > 0; s >>= 1) {
        if (tid < s) part[768 + tid] += part[768 + tid + s];
        __syncthreads();
      }
      const float inv = 1.0f / part[768];
      if (tid < DOn) {
        const float p = e * inv;
        astore(xn + (size_t)tid * Bn + b, p);            // note(next), transposed
        a.out[((size_t)b * TTn + t) * DOn + tid] = p;    // output
      }
    } else if (((t & 15) == 15) && t != (TTn - 1)) {
      // next step starts a new segment: reset h1/h2 inputs to dh1/dh2 (this pod)
      int i = (ht - 16) * NTHR + tid;                    // 0..8191
      int row = i >> 4, bl = i & 15;
      astore(xn + (size_t)(DOn + row) * Bn + b0 + bl, a.sdT[(size_t)row * Bn + b0 + bl]);
      astore(h2n + (size_t)row * Bn + b0 + bl, a.sdT[(size_t)(1024 + row) * Bn + b0 + bl]);
    }
    pbar(pod);
  }
}

extern "C" void kernel_launch(void* const* d_in, const int* in_sizes, int n_in,
                              void* d_out, int out_size, void* d_ws, size_t ws_size,
                              hipStream_t stream) {
  (void)in_sizes; (void)n_in; (void)out_size; (void)ws_size;
  KArgs a;
  a.z   = (const float*)d_in[0];
  a.Wz  = (const float*)d_in[3];  a.bz  = (const float*)d_in[4];
  // d_in[5] = cond_W1 unused (conductor input x0 == 0)
  a.cU1 = (const float*)d_in[6];  a.cb1 = (const float*)d_in[7];
  a.cW2 = (const float*)d_in[8];  a.cU2 = (const float*)d_in[9];  a.cb2 = (const float*)d_in[10];
  a.Wcd = (const float*)d_in[11]; a.bcd = (const float*)d_in[12];
  a.dW1 = (const float*)d_in[13]; a.dU1 = (const float*)d_in[14]; a.db1 = (const float*)d_in[15];
  a.dW2 = (const float*)d_in[16]; a.dU2 = (const float*)d_in[17]; a.db2 = (const float*)d_in[18];
  a.Wp  = (const float*)d_in[19]; a.bp  = (const float*)d_in[20];

  float* ws = (float*)d_ws;
  size_t off = 0;
  a.zT    = ws + off; off += (size_t)Hn * Bn;
  a.sT    = ws + off; off += (size_t)NGn * Bn;
  a.gbuf1 = ws + off; off += (size_t)NGn * Bn;
  a.gbuf2 = ws + off; off += (size_t)NGn * Bn;
  a.h1cT  = ws + off; off += (size_t)Hn * Bn;
  a.ceT   = ws + off; off += (size_t)Hn * Bn;
  a.sdT   = ws + off; off += (size_t)NGn * Bn;         // dh1|dc1|dh2|dc2
  a.beffT = ws + off; off += (size_t)NGn * Bn;         // permuted cols
  a.xbufA = ws + off; off += (size_t)2 * KAn * Bn;     // [note|h1] x2
  a.h2T   = ws + off; off += (size_t)2 * Hn * Bn;
  a.c1T   = ws + off; off += (size_t)Hn * Bn;
  a.c2T   = ws + off; off += (size_t)Hn * Bn;
  a.h2bk  = ws + off; off += (size_t)Bn * Hn;          // [b][k] for phase C
  a.db1p  = ws + off; off += (size_t)NGn;
  a.db2p  = ws + off; off += (size_t)NGn;
  a.WAp   = ws + off; off += (size_t)KAn * NGn;        // [note|h1] permuted
  a.WEp   = ws + off; off += (size_t)Hn * NGn;         // dW1 cond-emb part permuted
  a.WBp   = ws + off; off += (size_t)1024 * NGn;       // [dW2|dU2] permuted
  a.out   = (float*)d_out;

  hd_kernel<<<dim3(NBLK), dim3(NTHR), 0, stream>>>(a);
}

// Round 5
// 9315.894 us; speedup vs baseline: 9.2968x; 1.1328x over previous
//
#include <hip/hip_runtime.h>
#include <hip/hip_bf16.h>
#include <math.h>

// ---- dims ----
#define Bn    128
#define NGn   2048
#define TTn   256
#define DOn   176
#define NBLK  256
#define NTHR  1024

typedef unsigned int uint;
typedef unsigned long long u64;
using f32x4 = __attribute__((ext_vector_type(4))) float;
using s16x8 = __attribute__((ext_vector_type(8))) short;
union FR { uint u[4]; s16x8 s; };

// strides
#define XA_STR 90112    // 128*704  (uints)
#define XB_STR 131072   // 128*1024 (uints)

struct KA {
  const float *z,*Wz,*bz,*cU1,*cb1,*cW2,*cU2,*cb2,*Wcd,*bcd;
  const float *dW1,*dU1,*db1,*dW2,*dU2,*db2,*Wp,*bp;
  float *zT,*sT,*gbuf,*h1cT,*ceT,*sdT,*beffP,*db1P,*db2P,*WEp,*h2f,*out;
  uint *WAh,*WAl,*WBh,*WBl,*xApk,*xBpk,*dhApk,*dhBpk;
};

// ---- barrier state ----
__device__ unsigned g_cnt_l1[16 * 32];
__device__ unsigned g_cnt;
__device__ unsigned g_gen;
__device__ unsigned pod_leaf[4 * 8 * 32];
__device__ unsigned pod_root[4 * 32];
__device__ unsigned pod_gen[4 * 32];

__device__ __forceinline__ float sigm(float x) { return 1.0f / (1.0f + __expf(-x)); }

__device__ __forceinline__ float aloadF(const float* p) {
  return __hip_atomic_load(p, __ATOMIC_RELAXED, __HIP_MEMORY_SCOPE_AGENT);
}
__device__ __forceinline__ void astoreF(float* p, float v) {
  __hip_atomic_store(p, v, __ATOMIC_RELAXED, __HIP_MEMORY_SCOPE_AGENT);
}
__device__ __forceinline__ uint aloadU(const uint* p) {
  return __hip_atomic_load(p, __ATOMIC_RELAXED, __HIP_MEMORY_SCOPE_AGENT);
}
__device__ __forceinline__ void astoreU(uint* p, uint v) {
  __hip_atomic_store(p, v, __ATOMIC_RELAXED, __HIP_MEMORY_SCOPE_AGENT);
}
__device__ __forceinline__ u64 aload64(const u64* p) {
  return __hip_atomic_load(p, __ATOMIC_RELAXED, __HIP_MEMORY_SCOPE_AGENT);
}

// split v = hi + lo (both bf16, RNE)
__device__ __forceinline__ void split2(float v, unsigned short& h, unsigned short& l) {
  __hip_bfloat16 bh = __float2bfloat16(v);
  float hf = __bfloat162float(bh);
  __hip_bfloat16 bl = __float2bfloat16(v - hf);
  h = *(unsigned short*)&bh; l = *(unsigned short*)&bl;
}
__device__ __forceinline__ uint packsplit(float v) {
  unsigned short h, l; split2(v, h, l);
  return (uint)h | ((uint)l << 16);
}

// global barrier (preamble only)
__device__ __forceinline__ void gbar() {
  __syncthreads();
  if (threadIdx.x == 0) {
    asm volatile("s_waitcnt vmcnt(0)" ::: "memory");
    unsigned g0 = __hip_atomic_load(&g_gen, __ATOMIC_RELAXED, __HIP_MEMORY_SCOPE_AGENT);
    unsigned p1 = __hip_atomic_fetch_add(&g_cnt_l1[(blockIdx.x >> 4) * 32], 1u,
                                         __ATOMIC_RELAXED, __HIP_MEMORY_SCOPE_AGENT);
    if (p1 == 15u) {
      unsigned p2 = __hip_atomic_fetch_add(&g_cnt, 1u, __ATOMIC_RELAXED, __HIP_MEMORY_SCOPE_AGENT);
      if (p2 == 15u) {
        #pragma unroll
        for (int i = 0; i < 16; i++)
          __hip_atomic_store(&g_cnt_l1[i * 32], 0u, __ATOMIC_RELAXED, __HIP_MEMORY_SCOPE_AGENT);
        __hip_atomic_store(&g_cnt, 0u, __ATOMIC_RELAXED, __HIP_MEMORY_SCOPE_AGENT);
        asm volatile("s_waitcnt vmcnt(0)" ::: "memory");
        __hip_atomic_fetch_add(&g_gen, 1u, __ATOMIC_RELAXED, __HIP_MEMORY_SCOPE_AGENT);
      }
    }
    while (__hip_atomic_load(&g_gen, __ATOMIC_RELAXED, __HIP_MEMORY_SCOPE_AGENT) == g0)
      __builtin_amdgcn_s_sleep(1);
  }
  __syncthreads();
}

// pod barrier: 64 blocks = 8 leaves x 8
__device__ __forceinline__ void pbar(int mt, int j) {
  __syncthreads();
  if (threadIdx.x == 0) {
    asm volatile("s_waitcnt vmcnt(0)" ::: "memory");
    unsigned* gen = &pod_gen[mt * 32];
    unsigned g0 = __hip_atomic_load(gen, __ATOMIC_RELAXED, __HIP_MEMORY_SCOPE_AGENT);
    unsigned p = __hip_atomic_fetch_add(&pod_leaf[(mt * 8 + (j >> 3)) * 32], 1u,
                                        __ATOMIC_RELAXED, __HIP_MEMORY_SCOPE_AGENT);
    if (p == 7u) {
      unsigned q = __hip_atomic_fetch_add(&pod_root[mt * 32], 1u,
                                          __ATOMIC_RELAXED, __HIP_MEMORY_SCOPE_AGENT);
      if (q == 7u) {
        #pragma unroll
        for (int l = 0; l < 8; l++)
          __hip_atomic_store(&pod_leaf[(mt * 8 + l) * 32], 0u, __ATOMIC_RELAXED, __HIP_MEMORY_SCOPE_AGENT);
        __hip_atomic_store(&pod_root[mt * 32], 0u, __ATOMIC_RELAXED, __HIP_MEMORY_SCOPE_AGENT);
        asm volatile("s_waitcnt vmcnt(0)" ::: "memory");
        __hip_atomic_fetch_add(gen, 1u, __ATOMIC_RELAXED, __HIP_MEMORY_SCOPE_AGENT);
      }
    }
    while (__hip_atomic_load(gen, __ATOMIC_RELAXED, __HIP_MEMORY_SCOPE_AGENT) == g0) { }
  }
  __syncthreads();
}

// ---------------- preamble f32 helpers (round-4 proven) ----------------
__device__ __forceinline__ void stageN(float* __restrict__ xs, const float* __restrict__ X,
                                       int nrows, int b0, int tid) {
  for (int i = tid; i < nrows * 16; i += NTHR)
    xs[i] = aloadF(X + (size_t)(i >> 4) * Bn + b0 + (i & 15));
}

template<int KC>
__device__ __forceinline__ void gemm16(const float* __restrict__ Wb, int colbase,
                                       int kq, int cg, int bg,
                                       const float* __restrict__ xsrc, float acc[16]) {
  const float* wp = Wb + (size_t)(kq * KC) * NGn + colbase + cg * 4;
  const float* xp = xsrc + (kq * KC) * 16 + bg * 4;
  #pragma unroll 2
  for (int kk = 0; kk < KC; kk++) {
    const float4 w4 = *(const float4*)(wp);
    const float4 x4 = *(const float4*)(xp);
    acc[0]  = fmaf(w4.x, x4.x, acc[0]);  acc[1]  = fmaf(w4.x, x4.y, acc[1]);
    acc[2]  = fmaf(w4.x, x4.z, acc[2]);  acc[3]  = fmaf(w4.x, x4.w, acc[3]);
    acc[4]  = fmaf(w4.y, x4.x, acc[4]);  acc[5]  = fmaf(w4.y, x4.y, acc[5]);
    acc[6]  = fmaf(w4.y, x4.z, acc[6]);  acc[7]  = fmaf(w4.y, x4.w, acc[7]);
    acc[8]  = fmaf(w4.z, x4.x, acc[8]);  acc[9]  = fmaf(w4.z, x4.y, acc[9]);
    acc[10] = fmaf(w4.z, x4.z, acc[10]); acc[11] = fmaf(w4.z, x4.w, acc[11]);
    acc[12] = fmaf(w4.w, x4.x, acc[12]); acc[13] = fmaf(w4.w, x4.y, acc[13]);
    acc[14] = fmaf(w4.w, x4.z, acc[14]); acc[15] = fmaf(w4.w, x4.w, acc[15]);
    wp += NGn; xp += 16;
  }
}

__device__ __forceinline__ void pstore(float* __restrict__ part, int kq, int cg, int bg,
                                       const float acc[16]) {
  #pragma unroll
  for (int c = 0; c < 4; c++) {
    float* p = part + (size_t)(kq * 64 + cg * 4 + c) * 17 + bg * 4;
    *(float4*)p = make_float4(acc[c*4], acc[c*4+1], acc[c*4+2], acc[c*4+3]);
  }
}

template<int MODE>
__device__ __forceinline__ void epi_plain(const float* bias, float* out,
                                          int colbase, int b0, int tid,
                                          const float* __restrict__ part) {
  int cl = tid >> 4, bl = tid & 15;
  float s = 0.0f;
  #pragma unroll
  for (int w = 0; w < 8; w++) s += part[(w * 64 + cl) * 17 + bl];
  if (bias) s += bias[colbase + cl];
  if (MODE == 0) s = tanhf(s);
  astoreF(out + (size_t)(colbase + cl) * Bn + b0 + bl, s);
}

__device__ __forceinline__ void cond_nl(const float* gb, const float* cbias,
                                        const float* cin, float* hout, int bid, int tid) {
  int i = bid * NTHR + tid;
  if (i < 512 * Bn) {
    int hid = i >> 7, b = i & 127;
    float gi = aloadF(gb + (size_t)hid * Bn + b)            + cbias[hid];
    float gf = aloadF(gb + (size_t)(512 + hid) * Bn + b)    + cbias[512 + hid];
    float gg = aloadF(gb + (size_t)(1024 + hid) * Bn + b)   + cbias[1024 + hid];
    float go = aloadF(gb + (size_t)(1536 + hid) * Bn + b)   + cbias[1536 + hid];
    float cprev = aloadF(cin + (size_t)hid * Bn + b);
    float c = sigm(gf) * cprev + sigm(gi) * tanhf(gg);
    astoreF(hout + (size_t)hid * Bn + b, sigm(go) * tanhf(c));
  }
}

// ---------------- main-loop MFMA phases ----------------
// Tile per block: 32 gate-cols (hid 8j..8j+8 x 4 gates) x 32 batches.
// 16 waves = (mt in 0..1 = 16-batch M-tile, k8 in 0..7 = K slice).
// Frag layouts (mfma_f32_16x16x32_bf16): A(x): m=lane&15, k=(lane>>4)*8+e;
// B(w): n=lane&15, k=(lane>>4)*8+e; D: n=lane&15, m=(lane>>4)*4+reg.
struct MC {
  const uint *WAh,*WAl,*WBh,*WBl,*dhApk,*dhBpk;
  uint *xApk,*xBpk;
  const float *beffP,*db2P,*Wp,*bp;
  float *h2f,*out;
  float *gp, *cst;   // LDS: gp 8192 f32, cst 1024 f32 (c1|c2|dc1|dc2)
  int j, b0;
};

__device__ __forceinline__ void ldxfrag(const uint* xp, int idx, FR& xh, FR& xl) {
  const u64* p = (const u64*)(xp + idx);
  u64 d0 = aload64(p), d1 = aload64(p + 1), d2 = aload64(p + 2), d3 = aload64(p + 3);
  uint w0 = (uint)d0, w1 = (uint)(d0 >> 32), w2 = (uint)d1, w3 = (uint)(d1 >> 32);
  uint w4 = (uint)d2, w5 = (uint)(d2 >> 32), w6 = (uint)d3, w7 = (uint)(d3 >> 32);
  xh.u[0] = (w0 & 0xffffu) | (w1 << 16); xl.u[0] = (w0 >> 16) | (w1 & 0xffff0000u);
  xh.u[1] = (w2 & 0xffffu) | (w3 << 16); xl.u[1] = (w2 >> 16) | (w3 & 0xffff0000u);
  xh.u[2] = (w4 & 0xffffu) | (w5 << 16); xl.u[2] = (w4 >> 16) | (w5 & 0xffff0000u);
  xh.u[3] = (w6 & 0xffffu) | (w7 << 16); xl.u[3] = (w6 >> 16) | (w7 & 0xffff0000u);
}

__device__ __forceinline__ void phaseA(const MC& c, int t) {
  const int tid = threadIdx.x, wid = tid >> 6, lane = tid & 63;
  const int mt = wid & 1, k8 = wid >> 1;
  const int n16 = lane & 15, lhi = lane >> 4;
  const int par = t & 1; const bool rst = (t & 15) == 0;
  const uint* xA = c.xApk + par * XA_STR;
  f32x4 a0 = {0.f,0.f,0.f,0.f}, a1 = {0.f,0.f,0.f,0.f};
  const int rbase = (c.b0 + mt * 16 + n16) * 704 + lhi * 8;
  const uint* WH = c.WAh + (size_t)c.j * 11264;   // 22ks*2nt*256
  const uint* WL = c.WAl + (size_t)c.j * 11264;
  const int s = (k8 < 6) ? k8 * 3 : 18 + (k8 - 6) * 2;
  const int e = (k8 < 6) ? s + 3 : s + 2;
  for (int ks = s; ks < e; ks++) {
    const uint* xp = (rst && ks >= 6) ? c.dhApk : xA;
    FR xh, xl; ldxfrag(xp, rbase + ks * 32, xh, xl);
    FR wh0, wh1, wl0, wl1;
    *(uint4*)wh0.u = *(const uint4*)(WH + ks * 512 + lane * 4);
    *(uint4*)wh1.u = *(const uint4*)(WH + ks * 512 + 256 + lane * 4);
    *(uint4*)wl0.u = *(const uint4*)(WL + ks * 512 + lane * 4);
    *(uint4*)wl1.u = *(const uint4*)(WL + ks * 512 + 256 + lane * 4);
    a0 = __builtin_amdgcn_mfma_f32_16x16x32_bf16(xh.s, wh0.s, a0, 0, 0, 0);
    a1 = __builtin_amdgcn_mfma_f32_16x16x32_bf16(xh.s, wh1.s, a1, 0, 0, 0);
    a0 = __builtin_amdgcn_mfma_f32_16x16x32_bf16(xl.s, wh0.s, a0, 0, 0, 0);
    a1 = __builtin_amdgcn_mfma_f32_16x16x32_bf16(xl.s, wh1.s, a1, 0, 0, 0);
    a0 = __builtin_amdgcn_mfma_f32_16x16x32_bf16(xh.s, wl0.s, a0, 0, 0, 0);
    a1 = __builtin_amdgcn_mfma_f32_16x16x32_bf16(xh.s, wl1.s, a1, 0, 0, 0);
  }
  const int sl = (k8 * 2 + mt) * 2;
  *(f32x4*)&c.gp[(sl * 64 + lane) * 4] = a0;
  *(f32x4*)&c.gp[((sl + 1) * 64 + lane) * 4] = a1;
  __syncthreads();
  if (tid < 256) {
    const int h = tid >> 5, bl = tid & 31;
    const int mtE = bl >> 4, m = bl & 15;
    const int ntE = h >> 2, laneb = (m >> 2) * 16, reg = m & 3;
    float g4[4];
    #pragma unroll
    for (int gi = 0; gi < 4; gi++) {
      const int n = (h & 3) * 4 + gi;
      float sv = 0.f;
      #pragma unroll
      for (int kk = 0; kk < 8; kk++)
        sv += c.gp[(((kk * 2 + mtE) * 2 + ntE) * 64 + laneb + n) * 4 + reg];
      g4[gi] = sv + c.beffP[(size_t)((c.j * 8 + h) * 4 + gi) * Bn + (c.b0 + bl)];
    }
    float cprev = rst ? c.cst[512 + tid] : c.cst[tid];
    float cc = sigm(g4[1]) * cprev + sigm(g4[0]) * tanhf(g4[2]);
    c.cst[tid] = cc;
    float h1 = sigm(g4[3]) * tanhf(cc);
    uint pk = packsplit(h1);
    const int hid = c.j * 8 + h, bb = c.b0 + bl;
    astoreU(c.xBpk + par * XB_STR + bb * 1024 + hid, pk);
    astoreU(c.xApk + (par ^ 1) * XA_STR + bb * 704 + 192 + hid, pk);
  }
}

__device__ __forceinline__ void phaseB(const MC& c, int t) {
  const int tid = threadIdx.x, wid = tid >> 6, lane = tid & 63;
  const int mt = wid & 1, k8 = wid >> 1;
  const int n16 = lane & 15, lhi = lane >> 4;
  const int par = t & 1; const bool rst = (t & 15) == 0;
  const uint* xB = c.xBpk + par * XB_STR;
  f32x4 a0 = {0.f,0.f,0.f,0.f}, a1 = {0.f,0.f,0.f,0.f};
  const int rbase = (c.b0 + mt * 16 + n16) * 1024 + lhi * 8;
  const uint* WH = c.WBh + (size_t)c.j * 16384;   // 32ks*2nt*256
  const uint* WL = c.WBl + (size_t)c.j * 16384;
  const int s = k8 * 4, e = s + 4;
  for (int ks = s; ks < e; ks++) {
    const uint* xp = (rst && ks >= 16) ? c.dhBpk : xB;
    FR xh, xl; ldxfrag(xp, rbase + ks * 32, xh, xl);
    FR wh0, wh1, wl0, wl1;
    *(uint4*)wh0.u = *(const uint4*)(WH + ks * 512 + lane * 4);
    *(uint4*)wh1.u = *(const uint4*)(WH + ks * 512 + 256 + lane * 4);
    *(uint4*)wl0.u = *(const uint4*)(WL + ks * 512 + lane * 4);
    *(uint4*)wl1.u = *(const uint4*)(WL + ks * 512 + 256 + lane * 4);
    a0 = __builtin_amdgcn_mfma_f32_16x16x32_bf16(xh.s, wh0.s, a0, 0, 0, 0);
    a1 = __builtin_amdgcn_mfma_f32_16x16x32_bf16(xh.s, wh1.s, a1, 0, 0, 0);
    a0 = __builtin_amdgcn_mfma_f32_16x16x32_bf16(xl.s, wh0.s, a0, 0, 0, 0);
    a1 = __builtin_amdgcn_mfma_f32_16x16x32_bf16(xl.s, wh1.s, a1, 0, 0, 0);
    a0 = __builtin_amdgcn_mfma_f32_16x16x32_bf16(xh.s, wl0.s, a0, 0, 0, 0);
    a1 = __builtin_amdgcn_mfma_f32_16x16x32_bf16(xh.s, wl1.s, a1, 0, 0, 0);
  }
  const int sl = (k8 * 2 + mt) * 2;
  *(f32x4*)&c.gp[(sl * 64 + lane) * 4] = a0;
  *(f32x4*)&c.gp[((sl + 1) * 64 + lane) * 4] = a1;
  __syncthreads();
  if (tid < 256) {
    const int h = tid >> 5, bl = tid & 31;
    const int mtE = bl >> 4, m = bl & 15;
    const int ntE = h >> 2, laneb = (m >> 2) * 16, reg = m & 3;
    float g4[4];
    #pragma unroll
    for (int gi = 0; gi < 4; gi++) {
      const int n = (h & 3) * 4 + gi;
      float sv = 0.f;
      #pragma unroll
      for (int kk = 0; kk < 8; kk++)
        sv += c.gp[(((kk * 2 + mtE) * 2 + ntE) * 64 + laneb + n) * 4 + reg];
      g4[gi] = sv + c.db2P[(c.j * 8 + h) * 4 + gi];
    }
    float cprev = rst ? c.cst[768 + tid] : c.cst[256 + tid];
    float cc = sigm(g4[1]) * cprev + sigm(g4[0]) * tanhf(g4[2]);
    c.cst[256 + tid] = cc;
    float h2 = sigm(g4[3]) * tanhf(cc);
    const int hid = c.j * 8 + h, bb = c.b0 + bl;
    astoreF(c.h2f + (size_t)bb * 512 + hid, h2);
    astoreU(c.xBpk + (par ^ 1) * XB_STR + bb * 1024 + 512 + hid, packsplit(h2));
  }
}

__device__ __forceinline__ void phaseC(const MC& c, int t) {
  if (c.j >= 32) return;
  const int tid = threadIdx.x;
  const int par = t & 1;
  const int b = c.b0 + c.j;
  if (tid < 512) c.gp[tid] = aloadF(c.h2f + (size_t)b * 512 + tid);
  __syncthreads();
  const int o = tid & 255, kh = tid >> 8;     // 4 K-quarters of 128
  float acc = 0.f;
  if (o < DOn) {
    const float* wr = c.Wp + (size_t)(kh * 128) * DOn + o;
    #pragma unroll 4
    for (int k = 0; k < 128; k++)
      acc = fmaf(c.gp[kh * 128 + k], wr[(size_t)k * DOn], acc);
  }
  c.gp[512 + kh * 256 + o] = acc;
  __syncthreads();
  float lg = 0.f;
  if (tid < DOn)
    lg = c.gp[512 + tid] + c.gp[768 + tid] + c.gp[1024 + tid] + c.gp[1280 + tid] + c.bp[tid];
  if (tid < 256) c.gp[1536 + tid] = (tid < DOn) ? lg : -1e30f;
  __syncthreads();
  for (int s = 128; s > 0; s >>= 1) {
    if (tid < s) c.gp[1536 + tid] = fmaxf(c.gp[1536 + tid], c.gp[1536 + tid + s]);
    __syncthreads();
  }
  const float mx = c.gp[1536];
  float e = 0.f;
  if (tid < 256) { e = (tid < DOn) ? __expf(lg - mx) : 0.f; c.gp[1792 + tid] = e; }
  __syncthreads();
  for (int s = 128; s > 0; s >>= 1) {
    if (tid < s) c.gp[1792 + tid] += c.gp[1792 + tid + s];
    __syncthreads();
  }
  const float inv = 1.0f / c.gp[1792];
  if (tid < DOn) {
    const float p = e * inv;
    astoreU(c.xApk + (par ^ 1) * XA_STR + b * 704 + tid, packsplit(p));
    c.out[((size_t)b * TTn + t) * DOn + tid] = p;
  }
}

// ---------------- kernel ----------------
__global__ void __launch_bounds__(NTHR, 1)
hd_kernel(KA A) {
  __shared__ float buf[25088];   // preamble: xs[16384]+part[8704]; main: gp[8192]+cst[1024]
  float* xs = buf;
  float* part = buf + 16384;
  const int bid = blockIdx.x, tid = threadIdx.x;
  const int lane = tid & 63;
  const int kqP = tid >> 6, cgP = lane & 15, bgP = lane >> 4;   // preamble gemm (tid<512)
  const int rP = bid & 31, btP = bid >> 5;
  const int htP = (rP & 7) * 4 + (rP >> 3);
  const int colbaseP = htP * 64, b0P = btP * 16;

  // ---- P-1: transposes, permuted biases, WEp, WA frag planes, xA zero rows ----
  {
    const int i0 = bid * NTHR + tid;                 // 0..262143
    if (i0 < 512 * Bn) { int zb = i0 >> 9, zk = i0 & 511; astoreF(A.zT + (size_t)zk * Bn + zb, A.z[i0]); }
    if (i0 < NGn) {
      int hid = i0 >> 2, g = i0 & 3, sc = g * 512 + hid;
      astoreF(A.db1P + i0, A.db1[sc]);
      astoreF(A.db2P + i0, A.db2[sc]);
    }
    if (i0 < 49152) {      // zero note+pad rows of xApk, both parities
      int pp = i0 / 24576, rr = i0 % 24576;
      int b = rr / 192, k = rr % 192;
      astoreU(A.xApk + pp * XA_STR + b * 704 + k, 0u);
    }
    for (int i = i0; i < 512 * NGn; i += NBLK * NTHR) {   // WEp[k][c_p]
      int k = i >> 11, pc = i & 2047;
      int hid = pc >> 2, g = pc & 3;
      astoreF(A.WEp + i, A.dW1[(size_t)(176 + k) * NGn + g * 512 + hid]);
    }
    for (int i = i0; i < 720896; i += NBLK * NTHR) {      // WA frag planes (hi,lo)
      int q = i & 3, ln = (i >> 2) & 63, nt = (i >> 8) & 1, tt = i >> 9;
      int ks = tt % 22, jj = tt / 22;
      int n = ln & 15, lh = ln >> 4;
      int cl = nt * 16 + n, hid = jj * 8 + (cl >> 2), g = cl & 3, col = g * 512 + hid;
      uint hh = 0, ll = 0;
      #pragma unroll
      for (int e2 = 0; e2 < 2; e2++) {
        int k = ks * 32 + lh * 8 + q * 2 + e2;
        float w = (k < 176) ? A.dW1[(size_t)k * NGn + col]
                : (k < 192) ? 0.f : A.dU1[(size_t)(k - 192) * NGn + col];
        unsigned short sh, sl; split2(w, sh, sl);
        hh |= ((uint)sh) << (16 * e2); ll |= ((uint)sl) << (16 * e2);
      }
      astoreU(A.WAh + i, hh); astoreU(A.WAl + i, ll);
    }
  }
  gbar();
  // ---- pre0: sT = tanh(z @ Wz + bz) ----
  {
    stageN(xs, A.zT, 512, b0P, tid); __syncthreads();
    if (tid < 512) {
      float acc[16] = {0,0,0,0,0,0,0,0,0,0,0,0,0,0,0,0};
      gemm16<64>(A.Wz, colbaseP, kqP, cgP, bgP, xs, acc);
      pstore(part, kqP, cgP, bgP, acc);
    }
    __syncthreads();
    epi_plain<0>(A.bz, A.sT, colbaseP, b0P, tid, part);
  }
  gbar();
  // ---- pre1: conductor L1 gates = ch1 @ cU1 ----
  {
    stageN(xs, A.sT, 512, b0P, tid); __syncthreads();
    if (tid < 512) {
      float acc[16] = {0,0,0,0,0,0,0,0,0,0,0,0,0,0,0,0};
      gemm16<64>(A.cU1, colbaseP, kqP, cgP, bgP, xs, acc);
      pstore(part, kqP, cgP, bgP, acc);
    }
    __syncthreads();
    epi_plain<1>(nullptr, A.gbuf, colbaseP, b0P, tid, part);
  }
  gbar();
  cond_nl(A.gbuf, A.cb1, A.sT + (size_t)512 * Bn, A.h1cT, bid, tid);
  gbar();
  // ---- pre2: conductor L2 gates = h1c @ cW2 + ch2 @ cU2 ----
  {
    stageN(xs, A.h1cT, 512, b0P, tid);
    stageN(xs + 8192, A.sT + (size_t)1024 * Bn, 512, b0P, tid);
    __syncthreads();
    if (tid < 512) {
      float acc[16] = {0,0,0,0,0,0,0,0,0,0,0,0,0,0,0,0};
      gemm16<64>(A.cW2, colbaseP, kqP, cgP, bgP, xs, acc);
      gemm16<64>(A.cU2, colbaseP, kqP, cgP, bgP, xs + 8192, acc);
      pstore(part, kqP, cgP, bgP, acc);
    }
    __syncthreads();
    epi_plain<1>(nullptr, A.gbuf, colbaseP, b0P, tid, part);
  }
  gbar();
  cond_nl(A.gbuf, A.cb2, A.sT + (size_t)1536 * Bn, A.ceT, bid, tid);
  gbar();
  // ---- pre3: sdT = tanh(ce @ Wcd + bcd); beffP = db1P + ce @ WEp ----
  {
    stageN(xs, A.ceT, 512, b0P, tid); __syncthreads();
    if (tid < 512) {
      float acc[16] = {0,0,0,0,0,0,0,0,0,0,0,0,0,0,0,0};
      gemm16<64>(A.Wcd, colbaseP, kqP, cgP, bgP, xs, acc);
      pstore(part, kqP, cgP, bgP, acc);
    }
    __syncthreads();
    epi_plain<0>(A.bcd, A.sdT, colbaseP, b0P, tid, part);
    __syncthreads();
    if (tid < 512) {
      float acc[16] = {0,0,0,0,0,0,0,0,0,0,0,0,0,0,0,0};
      gemm16<64>(A.WEp, colbaseP, kqP, cgP, bgP, xs, acc);
      pstore(part, kqP, cgP, bgP, acc);
    }
    __syncthreads();
    epi_plain<1>(A.db1P, A.beffP, colbaseP, b0P, tid, part);
  }
  gbar();
  // ---- P4: WB frag planes (WBh overlaps WEp region), dh packs ----
  {
    const int i0 = bid * NTHR + tid;
    for (int i = i0; i < 1048576; i += NBLK * NTHR) {
      int q = i & 3, ln = (i >> 2) & 63, nt = (i >> 8) & 1, tt = i >> 9;
      int ks = tt & 31, jj = tt >> 5;
      int n = ln & 15, lh = ln >> 4;
      int cl = nt * 16 + n, hid = jj * 8 + (cl >> 2), g = cl & 3, col = g * 512 + hid;
      uint hh = 0, ll = 0;
      #pragma unroll
      for (int e2 = 0; e2 < 2; e2++) {
        int k = ks * 32 + lh * 8 + q * 2 + e2;
        float w = (k < 512) ? A.dW2[(size_t)k * NGn + col] : A.dU2[(size_t)(k - 512) * NGn + col];
        unsigned short sh, sl; split2(w, sh, sl);
        hh |= ((uint)sh) << (16 * e2); ll |= ((uint)sl) << (16 * e2);
      }
      astoreU(A.WBh + i, hh); astoreU(A.WBl + i, ll);
    }
    if (i0 < 512 * Bn) {
      int hid = i0 >> 7, b = i0 & 127;
      astoreU(A.dhApk + b * 704 + 192 + hid, packsplit(aloadF(A.sdT + (size_t)hid * Bn + b)));
      astoreU(A.dhBpk + b * 1024 + 512 + hid, packsplit(aloadF(A.sdT + (size_t)(1024 + hid) * Bn + b)));
    }
  }
  gbar();

  // ---- main loop ----
  MC c;
  c.WAh = A.WAh; c.WAl = A.WAl; c.WBh = A.WBh; c.WBl = A.WBl;
  c.dhApk = A.dhApk; c.dhBpk = A.dhBpk;
  c.xApk = A.xApk; c.xBpk = A.xBpk;
  c.beffP = A.beffP; c.db2P = A.db2P; c.Wp = A.Wp; c.bp = A.bp;
  c.h2f = A.h2f; c.out = A.out;
  c.gp = buf; c.cst = buf + 8192;
  c.j = bid & 63;
  const int mtp = bid >> 6;
  c.b0 = mtp * 32;
  // preload dc1/dc2 slices into LDS (c1/c2 written at first rst step before any read)
  if (tid < 256) {
    int h = tid >> 5, bl = tid & 31;
    int hid = c.j * 8 + h, b = c.b0 + bl;
    c.cst[512 + tid] = aloadF(A.sdT + (size_t)(512 + hid) * Bn + b);
    c.cst[768 + tid] = aloadF(A.sdT + (size_t)(1536 + hid) * Bn + b);
  }
  __syncthreads();

  for (int t = 0; t < TTn; t++) {
    phaseA(c, t);
    pbar(mtp, c.j);
    phaseB(c, t);
    pbar(mtp, c.j);
    phaseC(c, t);
    pbar(mtp, c.j);
  }
}

extern "C" void kernel_launch(void* const* d_in, const int* in_sizes, int n_in,
                              void* d_out, int out_size, void* d_ws, size_t ws_size,
                              hipStream_t stream) {
  (void)in_sizes; (void)n_in; (void)out_size; (void)ws_size;
  KA a;
  a.z   = (const float*)d_in[0];
  a.Wz  = (const float*)d_in[3];  a.bz  = (const float*)d_in[4];
  // d_in[5] = cond_W1 unused (conductor input x0 == 0)
  a.cU1 = (const float*)d_in[6];  a.cb1 = (const float*)d_in[7];
  a.cW2 = (const float*)d_in[8];  a.cU2 = (const float*)d_in[9];  a.cb2 = (const float*)d_in[10];
  a.Wcd = (const float*)d_in[11]; a.bcd = (const float*)d_in[12];
  a.dW1 = (const float*)d_in[13]; a.dU1 = (const float*)d_in[14]; a.db1 = (const float*)d_in[15];
  a.dW2 = (const float*)d_in[16]; a.dU2 = (const float*)d_in[17]; a.db2 = (const float*)d_in[18];
  a.Wp  = (const float*)d_in[19]; a.bp  = (const float*)d_in[20];

  float* ws = (float*)d_ws;
  size_t off = 0;
  a.zT    = ws + off; off += (size_t)512  * Bn;     //  65536
  a.sT    = ws + off; off += (size_t)NGn  * Bn;     // 262144
  a.gbuf  = ws + off; off += (size_t)NGn  * Bn;     // 262144
  a.h1cT  = ws + off; off += (size_t)512  * Bn;
  a.ceT   = ws + off; off += (size_t)512  * Bn;
  a.sdT   = ws + off; off += (size_t)NGn  * Bn;     // dh1|dc1|dh2|dc2
  a.beffP = ws + off; off += (size_t)NGn  * Bn;     // [c_p][b]
  a.db1P  = ws + off; off += (size_t)NGn;
  a.db2P  = ws + off; off += (size_t)NGn;
  a.WEp   = ws + off; off += (size_t)512 * NGn;     // 1048576 (aliased by WBh in P4)
  a.WBh   = (uint*)a.WEp;
  a.WBl   = (uint*)(ws + off); off += (size_t)1048576;
  a.WAh   = (uint*)(ws + off); off += (size_t)720896;
  a.WAl   = (uint*)(ws + off); off += (size_t)720896;
  a.xApk  = (uint*)(ws + off); off += (size_t)2 * XA_STR;
  a.xBpk  = (uint*)(ws + off); off += (size_t)2 * XB_STR;
  a.dhApk = (uint*)(ws + off); off += (size_t)XA_STR;
  a.dhBpk = (uint*)(ws + off); off += (size_t)XB_STR;
  a.h2f   = ws + off; off += (size_t)Bn * 512;
  a.out   = (float*)d_out;

  hd_kernel<<<dim3(NBLK), dim3(NTHR), 0, stream>>>(a);
}